// Round 1
// baseline (1238.918 us; speedup 1.0000x reference)
//
#include <hip/hip_runtime.h>
#include <math.h>

#define BB 2
#define CC 256
#define HW 96
#define PP 9216
#define KO 18
#define HEADS 8
#define NCH 36

// ws layout (float offsets), all 64B-aligned
#define OFF_O   0UL          // 2*18*9216            = 331776
#define IDX_O   331776UL     // int4 table: 2*9*9216*4 ints = 663552
#define WGT_O   995328UL     // float4 table          = 663552
#define WT_O    1658880UL    // Wd^T 2304*256         = 589824
#define QP_O    2248704UL    // q partials 2*2*256*9216 = 9437184
#define KV_O    11685888UL   // k,v 2*512*9216        = 9437184
#define INV_O   21123072UL   // 2*512                 = 1024
#define AP_O    21124096UL   // attn partials 2*8*36*1024 = 589824
#define AT_O    21713920UL   // attn softmaxed 2*8*1024 = 16384
#define MID_O   21730304UL   // mid 2*256*9216        = 4718592

// ---------------- Wd transpose: wt[k*256+o] = wd[o*2304+k] ----------------
__global__ __launch_bounds__(256) void k_transpose_wd(const float* __restrict__ wd,
                                                      float* __restrict__ wt) {
    int idx = blockIdx.x * 256 + threadIdx.x;
    if (idx >= 2304 * 256) return;
    int k = idx >> 8, o = idx & 255;
    wt[idx] = wd[o * 2304 + k];
}

// ---------------- pconv: offsets[b][18][9216] ----------------
__global__ __launch_bounds__(256) void k_pconv(const float* __restrict__ x,
                                               const float* __restrict__ wp,
                                               const float* __restrict__ bp,
                                               float* __restrict__ off) {
    int b = blockIdx.y;
    int p0 = blockIdx.x * 64;
    int t = threadIdx.x;
    int pl = t & 63, g = t >> 6;     // 4 c-groups (one per wave)
    int p = p0 + pl;
    int i = p / 96, j = p % 96;
    float acc[KO];
#pragma unroll
    for (int o = 0; o < KO; ++o) acc[o] = 0.f;
    const float* xb = x + (size_t)b * CC * PP;
    for (int c = g * 64; c < g * 64 + 64; ++c) {
        const float* xc = xb + (size_t)c * PP;
        float s[9];
#pragma unroll
        for (int n = 0; n < 9; ++n) {
            int ii = i + n / 3 - 1, jj = j + n % 3 - 1;
            s[n] = (ii >= 0 && ii < 96 && jj >= 0 && jj < 96) ? xc[ii * 96 + jj] : 0.f;
        }
#pragma unroll
        for (int o = 0; o < KO; ++o) {
            float a = 0.f;
#pragma unroll
            for (int n = 0; n < 9; ++n) a = fmaf(wp[(o * CC + c) * 9 + n], s[n], a);
            acc[o] += a;
        }
    }
    __shared__ float red[KO][64][4];
#pragma unroll
    for (int o = 0; o < KO; ++o) red[o][pl][g] = acc[o];
    __syncthreads();
    for (int idx = t; idx < KO * 64; idx += 256) {
        int o = idx >> 6, pq = idx & 63;
        float v = red[o][pq][0] + red[o][pq][1] + red[o][pq][2] + red[o][pq][3] + bp[o];
        off[((size_t)b * KO + o) * PP + p0 + pq] = v;
    }
}

// ---------------- bilinear table setup ----------------
__global__ __launch_bounds__(256) void k_bilin(const float* __restrict__ off,
                                               int4* __restrict__ idx4,
                                               float4* __restrict__ wgt4) {
    int idx = blockIdx.x * 256 + threadIdx.x;
    if (idx >= BB * 9 * PP) return;
    int p = idx % PP;
    int bn = idx / PP;
    int n = bn % 9, b = bn / 9;
    int i = p / 96, j = p % 96;
    float ox = off[((size_t)b * KO + n) * PP + p];
    float oy = off[((size_t)b * KO + 9 + n) * PP + p];
    float px = ox + (float)(n / 3 - 1) + (float)(i + 1);
    float py = oy + (float)(n % 3 - 1) + (float)(j + 1);
    float fx = floorf(px), fy = floorf(py);
    float qltx = fminf(fmaxf(fx, 0.f), 97.f);
    float qlty = fminf(fmaxf(fy, 0.f), 97.f);
    float qrbx = fminf(fmaxf(fx + 1.f, 0.f), 97.f);
    float qrby = fminf(fmaxf(fy + 1.f, 0.f), 97.f);
    float pxc = fminf(fmaxf(px, 0.f), 97.f);
    float pyc = fminf(fmaxf(py, 0.f), 97.f);
    float glt = (1.f + (qltx - pxc)) * (1.f + (qlty - pyc));
    float grb = (1.f - (qrbx - pxc)) * (1.f - (qrby - pyc));
    float glb = (1.f + (qltx - pxc)) * (1.f - (qrby - pyc));
    float grt = (1.f - (qrbx - pxc)) * (1.f + (qlty - pyc));
    int x0 = (int)qltx - 1, y0 = (int)qlty - 1;
    int x1 = (int)qrbx - 1, y1 = (int)qrby - 1;
    int4 id;
    id.x = (x0 >= 0 && x0 < 96 && y0 >= 0 && y0 < 96) ? x0 * 96 + y0 : -1;
    id.y = (x1 >= 0 && x1 < 96 && y1 >= 0 && y1 < 96) ? x1 * 96 + y1 : -1;
    id.z = (x0 >= 0 && x0 < 96 && y1 >= 0 && y1 < 96) ? x0 * 96 + y1 : -1;
    id.w = (x1 >= 0 && x1 < 96 && y0 >= 0 && y0 < 96) ? x1 * 96 + y0 : -1;
    idx4[idx] = id;
    wgt4[idx] = make_float4(glt, grb, glb, grt);
}

__device__ __forceinline__ float dsample(const float* __restrict__ xc, int4 id, float4 g) {
    float v = 0.f;
    if (id.x >= 0) v = fmaf(g.x, xc[id.x], v);
    if (id.y >= 0) v = fmaf(g.y, xc[id.y], v);
    if (id.z >= 0) v = fmaf(g.z, xc[id.z], v);
    if (id.w >= 0) v = fmaf(g.w, xc[id.w], v);
    return v;
}

// ---------------- fused deformable conv (c-split halves) ----------------
__global__ __launch_bounds__(256) void k_dconv(const float* __restrict__ x,
                                               const float* __restrict__ wt,
                                               const int4* __restrict__ idx4,
                                               const float4* __restrict__ wgt4,
                                               float* __restrict__ qpart) {
    int b = blockIdx.y;
    int half = blockIdx.z;
    int p0 = blockIdx.x * 64;
    int t = threadIdx.x;
    int to = t & 31;  // 8 o's at to*8
    int tp = t >> 5;  // 8 p's at tp*8
    __shared__ float A_lds[9][256];
    __shared__ float S_lds[9][64];

    // preload bilinear table entries (e = n*64 + pl)
    int4 id0, id1, id2 = make_int4(-1, -1, -1, -1);
    float4 g0, g1, g2 = make_float4(0, 0, 0, 0);
    {
        int n = t >> 6, pl = t & 63;
        size_t tb = ((size_t)b * 9 + n) * PP + p0 + pl;
        id0 = idx4[tb]; g0 = wgt4[tb];
        tb = ((size_t)b * 9 + n + 4) * PP + p0 + pl;
        id1 = idx4[tb]; g1 = wgt4[tb];
        if (t < 64) {
            tb = ((size_t)b * 9 + 8) * PP + p0 + t;
            id2 = idx4[tb]; g2 = wgt4[tb];
        }
    }
    float acc[8][8];
#pragma unroll
    for (int a = 0; a < 8; ++a)
#pragma unroll
        for (int bq = 0; bq < 8; ++bq) acc[a][bq] = 0.f;

    const float* xb = x + (size_t)b * CC * PP;
    int c0 = half * 128;
    for (int c = c0; c < c0 + 128; ++c) {
        const float* xc = xb + (size_t)c * PP;
#pragma unroll
        for (int kk = 0; kk < 9; ++kk)
            A_lds[kk][t] = wt[(c * 9 + kk) * 256 + t];
        {
            float v0 = dsample(xc, id0, g0);
            S_lds[t >> 6][t & 63] = v0;
            float v1 = dsample(xc, id1, g1);
            S_lds[(t >> 6) + 4][t & 63] = v1;
            if (t < 64) S_lds[8][t] = dsample(xc, id2, g2);
        }
        __syncthreads();
#pragma unroll
        for (int kk = 0; kk < 9; ++kk) {
            const float4 a0 = *(const float4*)&A_lds[kk][to * 8];
            const float4 a1 = *(const float4*)&A_lds[kk][to * 8 + 4];
            const float4 b0 = *(const float4*)&S_lds[kk][tp * 8];
            const float4 b1 = *(const float4*)&S_lds[kk][tp * 8 + 4];
            float av[8] = {a0.x, a0.y, a0.z, a0.w, a1.x, a1.y, a1.z, a1.w};
            float bv[8] = {b0.x, b0.y, b0.z, b0.w, b1.x, b1.y, b1.z, b1.w};
#pragma unroll
            for (int oo = 0; oo < 8; ++oo)
#pragma unroll
                for (int pj = 0; pj < 8; ++pj)
                    acc[oo][pj] = fmaf(av[oo], bv[pj], acc[oo][pj]);
        }
        __syncthreads();
    }
    float* qh = qpart + (size_t)half * BB * CC * PP;
#pragma unroll
    for (int oo = 0; oo < 8; ++oo) {
        int o = to * 8 + oo;
        float* qrow = qh + ((size_t)b * CC + o) * PP + p0 + tp * 8;
        *(float4*)&qrow[0] = make_float4(acc[oo][0], acc[oo][1], acc[oo][2], acc[oo][3]);
        *(float4*)&qrow[4] = make_float4(acc[oo][4], acc[oo][5], acc[oo][6], acc[oo][7]);
    }
}

// ---------------- generic fp32 GEMM: C[b] = A(MxKc) * B[b](KcxPP) ----------------
__global__ __launch_bounds__(256) void k_gemm(const float* __restrict__ A,
                                              const float* __restrict__ Bsrc,
                                              float* __restrict__ Cdst,
                                              int M, int Kc) {
    int b = blockIdx.z;
    int n0 = blockIdx.x * 128;
    int m0 = blockIdx.y * 128;
    const float* Bb = Bsrc + (size_t)b * Kc * PP;
    float* Cb = Cdst + (size_t)b * M * PP;
    __shared__ float As[16][132];
    __shared__ float Bs[16][132];
    int t = threadIdx.x;
    int tm = t & 15, tn = t >> 4;
    float acc[8][8];
#pragma unroll
    for (int a = 0; a < 8; ++a)
#pragma unroll
        for (int c = 0; c < 8; ++c) acc[a][c] = 0.f;

    for (int k0 = 0; k0 < Kc; k0 += 16) {
#pragma unroll
        for (int r = 0; r < 2; ++r) {
            int m = (t >> 2) + r * 64;
            int kq = (t & 3) * 4;
            float4 va = *(const float4*)&A[(size_t)(m0 + m) * Kc + k0 + kq];
            As[kq + 0][m] = va.x; As[kq + 1][m] = va.y;
            As[kq + 2][m] = va.z; As[kq + 3][m] = va.w;
        }
#pragma unroll
        for (int r = 0; r < 2; ++r) {
            int kB = t >> 4;
            int nq = (t & 15) * 8 + r * 4;
            *(float4*)&Bs[kB][nq] = *(const float4*)&Bb[(size_t)(k0 + kB) * PP + n0 + nq];
        }
        __syncthreads();
#pragma unroll
        for (int kk = 0; kk < 16; ++kk) {
            const float4 a0 = *(const float4*)&As[kk][tm * 8];
            const float4 a1 = *(const float4*)&As[kk][tm * 8 + 4];
            const float4 b0 = *(const float4*)&Bs[kk][tn * 8];
            const float4 b1 = *(const float4*)&Bs[kk][tn * 8 + 4];
            float av[8] = {a0.x, a0.y, a0.z, a0.w, a1.x, a1.y, a1.z, a1.w};
            float bv[8] = {b0.x, b0.y, b0.z, b0.w, b1.x, b1.y, b1.z, b1.w};
#pragma unroll
            for (int i = 0; i < 8; ++i)
#pragma unroll
                for (int j = 0; j < 8; ++j)
                    acc[i][j] = fmaf(av[i], bv[j], acc[i][j]);
        }
        __syncthreads();
    }
#pragma unroll
    for (int i = 0; i < 8; ++i) {
        float* crow = Cb + (size_t)(m0 + tm * 8 + i) * PP + n0 + tn * 8;
        *(float4*)&crow[0] = make_float4(acc[i][0], acc[i][1], acc[i][2], acc[i][3]);
        *(float4*)&crow[4] = make_float4(acc[i][4], acc[i][5], acc[i][6], acc[i][7]);
    }
}

// ---------------- row norms of k,v -> 1/max(||row||, 1e-12) ----------------
__global__ __launch_bounds__(256) void k_norms(const float* __restrict__ kv,
                                               float* __restrict__ invn) {
    int b = blockIdx.y, r = blockIdx.x;  // r in 0..511
    const float* row = kv + ((size_t)b * 512 + r) * PP;
    int t = threadIdx.x;
    float s = 0.f;
    for (int p = t * 4; p < PP; p += 1024) {
        float4 v = *(const float4*)&row[p];
        s += v.x * v.x + v.y * v.y + v.z * v.z + v.w * v.w;
    }
#pragma unroll
    for (int o = 32; o > 0; o >>= 1) s += __shfl_down(s, o, 64);
    __shared__ float wsum[4];
    if ((t & 63) == 0) wsum[t >> 6] = s;
    __syncthreads();
    if (t == 0) {
        float tot = wsum[0] + wsum[1] + wsum[2] + wsum[3];
        invn[b * 512 + r] = 1.f / fmaxf(sqrtf(tot), 1e-12f);
    }
}

// ---------------- attention score partials: q . k over 256-p chunks ----------------
__global__ __launch_bounds__(256) void k_attn_part(const float* __restrict__ qp,
                                                   const float* __restrict__ kv,
                                                   float* __restrict__ apart) {
    int ch = blockIdx.x, h = blockIdx.y, b = blockIdx.z;
    int t = threadIdx.x;
    int d = t & 31, cg = t >> 5;
    __shared__ float qs[32][37], ks[32][37];
    float acc[4] = {0.f, 0.f, 0.f, 0.f};
    const float* q0 = qp + ((size_t)b * CC + h * 32) * PP;
    const float* q1 = q0 + (size_t)BB * CC * PP;
    const float* kb = kv + ((size_t)b * 512 + h * 32) * PP;
    int r = t >> 3, cq = (t & 7) * 4;
    for (int po = ch * 256; po < ch * 256 + 256; po += 32) {
        float4 va = *(const float4*)&q0[(size_t)r * PP + po + cq];
        float4 vb = *(const float4*)&q1[(size_t)r * PP + po + cq];
        qs[r][cq + 0] = va.x + vb.x; qs[r][cq + 1] = va.y + vb.y;
        qs[r][cq + 2] = va.z + vb.z; qs[r][cq + 3] = va.w + vb.w;
        float4 vk = *(const float4*)&kb[(size_t)r * PP + po + cq];
        ks[r][cq + 0] = vk.x; ks[r][cq + 1] = vk.y;
        ks[r][cq + 2] = vk.z; ks[r][cq + 3] = vk.w;
        __syncthreads();
#pragma unroll
        for (int pq = 0; pq < 32; ++pq) {
            float kvv = ks[d][pq];
#pragma unroll
            for (int i = 0; i < 4; ++i)
                acc[i] = fmaf(qs[cg * 4 + i][pq], kvv, acc[i]);
        }
        __syncthreads();
    }
    float* ap = apart + (((size_t)(b * 8 + h) * NCH + ch) << 10);
#pragma unroll
    for (int i = 0; i < 4; ++i) ap[(cg * 4 + i) * 32 + d] = acc[i];
}

// ---------------- reduce partials, temp*invnk scale, softmax, *invnv ----------------
__global__ __launch_bounds__(256) void k_attn_fin(const float* __restrict__ apart,
                                                  const float* __restrict__ invn,
                                                  const float* __restrict__ temp,
                                                  float* __restrict__ attns) {
    int h = blockIdx.x, b = blockIdx.y;
    int t = threadIdx.x;
    __shared__ float A[32][33];
    const float* ap = apart + ((size_t)(b * 8 + h) * NCH << 10);
    float th = temp[h];
    for (int e = t; e < 1024; e += 256) {
        float s = 0.f;
        for (int chn = 0; chn < NCH; ++chn) s += ap[chn * 1024 + e];
        int c = e >> 5, d = e & 31;
        A[c][d] = s * th * invn[b * 512 + h * 32 + d];
    }
    __syncthreads();
    if (t < 32) {
        int c = t;
        float m = -INFINITY;
#pragma unroll
        for (int d = 0; d < 32; ++d) m = fmaxf(m, A[c][d]);
        float sum = 0.f;
#pragma unroll
        for (int d = 0; d < 32; ++d) sum += expf(A[c][d] - m);
        float inv = 1.f / sum;
        float* at = attns + ((size_t)(b * 8 + h) << 10) + c * 32;
#pragma unroll
        for (int d = 0; d < 32; ++d)
            at[d] = expf(A[c][d] - m) * inv * invn[b * 512 + 256 + h * 32 + d];
    }
}

// ---------------- mid = attnS @ v (per head, K=32) ----------------
__global__ __launch_bounds__(256) void k_outmid(const float* __restrict__ attns,
                                                const float* __restrict__ kv,
                                                float* __restrict__ mid) {
    int pt = blockIdx.x, h = blockIdx.y, b = blockIdx.z;
    int p0 = pt * 128;
    int t = threadIdx.x;
    int tp = t & 31, tc = t >> 5;
    __shared__ float vs[32][132];
    __shared__ float as[32][33];
    for (int e = t; e < 1024; e += 256)
        as[e >> 5][e & 31] = attns[((size_t)(b * 8 + h) << 10) + e];
    {
        int r = t & 31;
        int c0 = (t >> 5) * 16;
        const float* vrow = kv + ((size_t)b * 512 + 256 + h * 32 + r) * PP + p0;
#pragma unroll
        for (int kq = 0; kq < 4; ++kq)
            *(float4*)&vs[r][c0 + kq * 4] = *(const float4*)&vrow[c0 + kq * 4];
    }
    __syncthreads();
    float acc[4][4];
#pragma unroll
    for (int i = 0; i < 4; ++i)
#pragma unroll
        for (int j = 0; j < 4; ++j) acc[i][j] = 0.f;
#pragma unroll
    for (int d = 0; d < 32; ++d) {
        float4 bv = *(const float4*)&vs[d][tp * 4];
#pragma unroll
        for (int i = 0; i < 4; ++i) {
            float a = as[tc * 4 + i][d];
            acc[i][0] = fmaf(a, bv.x, acc[i][0]);
            acc[i][1] = fmaf(a, bv.y, acc[i][1]);
            acc[i][2] = fmaf(a, bv.z, acc[i][2]);
            acc[i][3] = fmaf(a, bv.w, acc[i][3]);
        }
    }
#pragma unroll
    for (int i = 0; i < 4; ++i) {
        float* mrow = mid + ((size_t)b * CC + h * 32 + tc * 4 + i) * PP + p0 + tp * 4;
        *(float4*)mrow = make_float4(acc[i][0], acc[i][1], acc[i][2], acc[i][3]);
    }
}

extern "C" void kernel_launch(void* const* d_in, const int* in_sizes, int n_in,
                              void* d_out, int out_size, void* d_ws, size_t ws_size,
                              hipStream_t stream) {
    const float* x     = (const float*)d_in[0];
    const float* wp    = (const float*)d_in[1];
    const float* bp    = (const float*)d_in[2];
    const float* wd    = (const float*)d_in[3];
    const float* wqkv  = (const float*)d_in[4];
    const float* temp  = (const float*)d_in[5];
    const float* wproj = (const float*)d_in[6];
    float* out = (float*)d_out;
    float* ws  = (float*)d_ws;

    float* off   = ws + OFF_O;
    int4*  idx4  = (int4*)(ws + IDX_O);
    float4* wgt4 = (float4*)(ws + WGT_O);
    float* wt    = ws + WT_O;
    float* qpart = ws + QP_O;
    float* kv    = ws + KV_O;
    float* invn  = ws + INV_O;
    float* apart = ws + AP_O;
    float* attns = ws + AT_O;
    float* mid   = ws + MID_O;

    k_transpose_wd<<<2304, 256, 0, stream>>>(wd, wt);
    k_pconv<<<dim3(144, BB), 256, 0, stream>>>(x, wp, bp, off);
    k_bilin<<<(BB * 9 * PP + 255) / 256, 256, 0, stream>>>(off, idx4, wgt4);
    k_dconv<<<dim3(144, BB, 2), 256, 0, stream>>>(x, wt, idx4, wgt4, qpart);
    k_gemm<<<dim3(72, 4, BB), 256, 0, stream>>>(wqkv + 256 * 256, x, kv, 512, 256);
    k_norms<<<dim3(512, BB), 256, 0, stream>>>(kv, invn);
    k_attn_part<<<dim3(NCH, HEADS, BB), 256, 0, stream>>>(qpart, kv, apart);
    k_attn_fin<<<dim3(HEADS, BB), 256, 0, stream>>>(apart, invn, temp, attns);
    k_outmid<<<dim3(72, HEADS, BB), 256, 0, stream>>>(attns, kv, mid);
    k_gemm<<<dim3(72, 2, BB), 256, 0, stream>>>(wproj, mid, out, 256, 256);
}

// Round 2
// 650.210 us; speedup vs baseline: 1.9054x; 1.9054x over previous
//
#include <hip/hip_runtime.h>
#include <math.h>

#define BB 2
#define CC 256
#define HW 96
#define PP 9216
#define KO 18
#define HEADS 8
#define NCH 36

typedef short bf16x8 __attribute__((ext_vector_type(8)));
typedef float f32x4 __attribute__((ext_vector_type(4)));

// ws layout (float offsets), all 64B-aligned
#define OFF_O   0UL          // 2*18*9216            = 331776
#define IDX_O   331776UL     // int4 table: 2*9*9216*4 ints = 663552
#define WGT_O   995328UL     // float4 table          = 663552
#define WT_O    1658880UL    // wt_hi + wt_lo, 2 x 589824 ushort = 589824 floats
#define QP_O    2248704UL    // q partials 2*2*256*9216 = 9437184
#define KV_O    11685888UL   // k,v 2*512*9216        = 9437184
#define INV_O   21123072UL   // 2*512                 = 1024
#define AP_O    21124096UL   // attn partials 2*8*36*1024 = 589824
#define AT_O    21713920UL   // attn softmaxed 2*8*1024 = 16384
#define MID_O   21730304UL   // mid 2*256*9216        = 4718592

__device__ __forceinline__ ushort f2bf_rne(float f) {
    unsigned u = __float_as_uint(f);
    unsigned r = (u + 0x7FFFu + ((u >> 16) & 1u)) >> 16;
    return (ushort)r;
}
__device__ __forceinline__ float bf2f(ushort h) {
    return __uint_as_float(((unsigned)h) << 16);
}
__device__ __forceinline__ void gload_lds16(const void* g, void* l) {
    __builtin_amdgcn_global_load_lds((const __attribute__((address_space(1))) void*)g,
                                     (__attribute__((address_space(3))) void*)l, 16, 0, 0);
}

// ---------------- prep: wd[o][c][kk] -> wt_hi/lo[kk][o][c] (split bf16) ------
__global__ __launch_bounds__(256) void k_prep_wt(const float* __restrict__ wd,
                                                 ushort* __restrict__ wt_hi,
                                                 ushort* __restrict__ wt_lo) {
    int idx = blockIdx.x * 256 + threadIdx.x;
    if (idx >= 9 * 256 * 256) return;
    int c = idx & 255, o = (idx >> 8) & 255, kk = idx >> 16;
    float v = wd[o * 2304 + c * 9 + kk];
    ushort h = f2bf_rne(v);
    float lo = v - bf2f(h);
    wt_hi[idx] = h;
    wt_lo[idx] = f2bf_rne(lo);
}

// ---------------- pconv: offsets[b][18][9216] ----------------
__global__ __launch_bounds__(256) void k_pconv(const float* __restrict__ x,
                                               const float* __restrict__ wp,
                                               const float* __restrict__ bp,
                                               float* __restrict__ off) {
    int b = blockIdx.y;
    int p0 = blockIdx.x * 64;
    int t = threadIdx.x;
    int pl = t & 63, g = t >> 6;
    int p = p0 + pl;
    int i = p / 96, j = p % 96;
    float acc[KO];
#pragma unroll
    for (int o = 0; o < KO; ++o) acc[o] = 0.f;
    const float* xb = x + (size_t)b * CC * PP;
    for (int c = g * 64; c < g * 64 + 64; ++c) {
        const float* xc = xb + (size_t)c * PP;
        float s[9];
#pragma unroll
        for (int n = 0; n < 9; ++n) {
            int ii = i + n / 3 - 1, jj = j + n % 3 - 1;
            s[n] = (ii >= 0 && ii < 96 && jj >= 0 && jj < 96) ? xc[ii * 96 + jj] : 0.f;
        }
#pragma unroll
        for (int o = 0; o < KO; ++o) {
            float a = 0.f;
#pragma unroll
            for (int n = 0; n < 9; ++n) a = fmaf(wp[(o * CC + c) * 9 + n], s[n], a);
            acc[o] += a;
        }
    }
    __shared__ float red[KO][64][4];
#pragma unroll
    for (int o = 0; o < KO; ++o) red[o][pl][g] = acc[o];
    __syncthreads();
    for (int idx = t; idx < KO * 64; idx += 256) {
        int o = idx >> 6, pq = idx & 63;
        float v = red[o][pq][0] + red[o][pq][1] + red[o][pq][2] + red[o][pq][3] + bp[o];
        off[((size_t)b * KO + o) * PP + p0 + pq] = v;
    }
}

// ---------------- bilinear table: always-valid index, zero weight if OOB -----
__global__ __launch_bounds__(256) void k_bilin(const float* __restrict__ off,
                                               int4* __restrict__ idx4,
                                               float4* __restrict__ wgt4) {
    int idx = blockIdx.x * 256 + threadIdx.x;
    if (idx >= BB * 9 * PP) return;
    int p = idx % PP;
    int bn = idx / PP;
    int n = bn % 9, b = bn / 9;
    int i = p / 96, j = p % 96;
    float ox = off[((size_t)b * KO + n) * PP + p];
    float oy = off[((size_t)b * KO + 9 + n) * PP + p];
    float px = ox + (float)(n / 3 - 1) + (float)(i + 1);
    float py = oy + (float)(n % 3 - 1) + (float)(j + 1);
    float fx = floorf(px), fy = floorf(py);
    float qltx = fminf(fmaxf(fx, 0.f), 97.f);
    float qlty = fminf(fmaxf(fy, 0.f), 97.f);
    float qrbx = fminf(fmaxf(fx + 1.f, 0.f), 97.f);
    float qrby = fminf(fmaxf(fy + 1.f, 0.f), 97.f);
    float pxc = fminf(fmaxf(px, 0.f), 97.f);
    float pyc = fminf(fmaxf(py, 0.f), 97.f);
    float glt = (1.f + (qltx - pxc)) * (1.f + (qlty - pyc));
    float grb = (1.f - (qrbx - pxc)) * (1.f - (qrby - pyc));
    float glb = (1.f + (qltx - pxc)) * (1.f - (qrby - pyc));
    float grt = (1.f - (qrbx - pxc)) * (1.f + (qlty - pyc));
    int x0 = (int)qltx - 1, y0 = (int)qlty - 1;
    int x1 = (int)qrbx - 1, y1 = (int)qrby - 1;
    bool vlt = (x0 >= 0 && x0 < 96 && y0 >= 0 && y0 < 96);
    bool vrb = (x1 >= 0 && x1 < 96 && y1 >= 0 && y1 < 96);
    bool vlb = (x0 >= 0 && x0 < 96 && y1 >= 0 && y1 < 96);
    bool vrt = (x1 >= 0 && x1 < 96 && y0 >= 0 && y0 < 96);
    int4 id;
    id.x = vlt ? x0 * 96 + y0 : 0;
    id.y = vrb ? x1 * 96 + y1 : 0;
    id.z = vlb ? x0 * 96 + y1 : 0;
    id.w = vrt ? x1 * 96 + y0 : 0;
    idx4[idx] = id;
    wgt4[idx] = make_float4(vlt ? glt : 0.f, vrb ? grb : 0.f,
                            vlb ? glb : 0.f, vrt ? grt : 0.f);
}

// ---------------- deformable conv as implicit-GEMM MFMA (split bf16) ---------
// BM=256 (all o), BN=64 pixels, K ordered [kk][c], c-split halves of 128.
// 4 waves, wave tile 64(M) x 64(N): 16 frags, 48 MFMA per K-step of 32.
__global__ __launch_bounds__(256) void k_dconv(const float* __restrict__ x,
                                               const ushort* __restrict__ wt_hi,
                                               const ushort* __restrict__ wt_lo,
                                               const int4* __restrict__ idx4,
                                               const float4* __restrict__ wgt4,
                                               float* __restrict__ qpart) {
    int b = blockIdx.y;
    int half = blockIdx.z;
    int p0 = blockIdx.x * 64;
    int t = threadIdx.x;
    int l = t & 63, w = t >> 6;
    int lrow = l & 15, lhi = l >> 4;
    int obase = w * 64;
    int p = t & 63;      // pixel for sample generation
    int cg = t >> 6;     // c-group for sample generation (8 c's)

    __shared__ __align__(16) ushort Ah[256 * 32];
    __shared__ __align__(16) ushort Al[256 * 32];
    __shared__ __align__(16) ushort Sh[64 * 40];   // stride 40: pad 8
    __shared__ __align__(16) ushort Sl[64 * 40];

    f32x4 acc[4][4];
#pragma unroll
    for (int mf = 0; mf < 4; ++mf)
#pragma unroll
        for (int nf = 0; nf < 4; ++nf) acc[mf][nf] = (f32x4)0.f;

    const float* xb = x + (size_t)b * CC * PP;

    for (int kk = 0; kk < 9; ++kk) {
        size_t tb = ((size_t)b * 9 + kk) * PP + p0 + p;
        int4 id = idx4[tb];
        float4 g4 = wgt4[tb];
#pragma unroll 1
        for (int cs = 0; cs < 4; ++cs) {
            int c0 = half * 128 + cs * 32;
            __syncthreads();   // previous step's reads done
            // --- stage A hi/lo via global_load_lds (linear dest, swizzled src)
#pragma unroll
            for (int r = 0; r < 4; ++r) {
                int u = r * 256 + t;          // 16B unit
                int o = u >> 2, kb = u & 3;
                int sw = kb ^ ((o >> 1) & 3);
                size_t gidx = ((size_t)(kk * 256 + o) << 8) + c0 + sw * 8;
                gload_lds16(wt_hi + gidx, &Ah[u * 8]);
            }
#pragma unroll
            for (int r = 0; r < 4; ++r) {
                int u = r * 256 + t;
                int o = u >> 2, kb = u & 3;
                int sw = kb ^ ((o >> 1) & 3);
                size_t gidx = ((size_t)(kk * 256 + o) << 8) + c0 + sw * 8;
                gload_lds16(wt_lo + gidx, &Al[u * 8]);
            }
            // --- gather-generate S tile (8 c's per thread, same pixel)
            const float* xp0 = xb + (size_t)(c0 + cg * 8) * PP;
            bf16x8 vh, vl;
#pragma unroll
            for (int i = 0; i < 8; ++i) {
                const float* xc = xp0 + (size_t)i * PP;
                float v = g4.x * xc[id.x];
                v = fmaf(g4.y, xc[id.y], v);
                v = fmaf(g4.z, xc[id.z], v);
                v = fmaf(g4.w, xc[id.w], v);
                ushort h = f2bf_rne(v);
                vh[i] = (short)h;
                vl[i] = (short)f2bf_rne(v - bf2f(h));
            }
            *(bf16x8*)&Sh[p * 40 + cg * 8] = vh;
            *(bf16x8*)&Sl[p * 40 + cg * 8] = vl;
            __syncthreads();   // staging + ds_writes visible
            // --- compute: 16 frags x 3 terms
            bf16x8 Bh4[4], Bl4[4];
#pragma unroll
            for (int nf = 0; nf < 4; ++nf) {
                Bh4[nf] = *(const bf16x8*)&Sh[(nf * 16 + lrow) * 40 + lhi * 8];
                Bl4[nf] = *(const bf16x8*)&Sl[(nf * 16 + lrow) * 40 + lhi * 8];
            }
#pragma unroll
            for (int mf = 0; mf < 4; ++mf) {
                int o = obase + mf * 16 + lrow;
                int sw = lhi ^ ((o >> 1) & 3);
                bf16x8 ah = *(const bf16x8*)&Ah[o * 32 + sw * 8];
                bf16x8 al = *(const bf16x8*)&Al[o * 32 + sw * 8];
#pragma unroll
                for (int nf = 0; nf < 4; ++nf) {
                    acc[mf][nf] = __builtin_amdgcn_mfma_f32_16x16x32_bf16(ah, Bh4[nf], acc[mf][nf], 0, 0, 0);
                    acc[mf][nf] = __builtin_amdgcn_mfma_f32_16x16x32_bf16(ah, Bl4[nf], acc[mf][nf], 0, 0, 0);
                    acc[mf][nf] = __builtin_amdgcn_mfma_f32_16x16x32_bf16(al, Bh4[nf], acc[mf][nf], 0, 0, 0);
                }
            }
        }
    }
    // --- write q partial
    float* qh = qpart + (size_t)half * BB * CC * PP + (size_t)b * CC * PP;
#pragma unroll
    for (int mf = 0; mf < 4; ++mf)
#pragma unroll
        for (int nf = 0; nf < 4; ++nf)
#pragma unroll
            for (int j = 0; j < 4; ++j)
                qh[(size_t)(obase + mf * 16 + lhi * 4 + j) * PP + p0 + nf * 16 + lrow] =
                    acc[mf][nf][j];
}

// ---------------- generic fp32 GEMM: C[b] = A(MxKc) * B[b](KcxPP) ----------------
__global__ __launch_bounds__(256) void k_gemm(const float* __restrict__ A,
                                              const float* __restrict__ Bsrc,
                                              float* __restrict__ Cdst,
                                              int M, int Kc) {
    int b = blockIdx.z;
    int n0 = blockIdx.x * 128;
    int m0 = blockIdx.y * 128;
    const float* Bb = Bsrc + (size_t)b * Kc * PP;
    float* Cb = Cdst + (size_t)b * M * PP;
    __shared__ float As[16][132];
    __shared__ float Bs[16][132];
    int t = threadIdx.x;
    int tm = t & 15, tn = t >> 4;
    float acc[8][8];
#pragma unroll
    for (int a = 0; a < 8; ++a)
#pragma unroll
        for (int c = 0; c < 8; ++c) acc[a][c] = 0.f;

    for (int k0 = 0; k0 < Kc; k0 += 16) {
#pragma unroll
        for (int r = 0; r < 2; ++r) {
            int m = (t >> 2) + r * 64;
            int kq = (t & 3) * 4;
            float4 va = *(const float4*)&A[(size_t)(m0 + m) * Kc + k0 + kq];
            As[kq + 0][m] = va.x; As[kq + 1][m] = va.y;
            As[kq + 2][m] = va.z; As[kq + 3][m] = va.w;
        }
#pragma unroll
        for (int r = 0; r < 2; ++r) {
            int kB = t >> 4;
            int nq = (t & 15) * 8 + r * 4;
            *(float4*)&Bs[kB][nq] = *(const float4*)&Bb[(size_t)(k0 + kB) * PP + n0 + nq];
        }
        __syncthreads();
#pragma unroll
        for (int kk = 0; kk < 16; ++kk) {
            const float4 a0 = *(const float4*)&As[kk][tm * 8];
            const float4 a1 = *(const float4*)&As[kk][tm * 8 + 4];
            const float4 b0 = *(const float4*)&Bs[kk][tn * 8];
            const float4 b1 = *(const float4*)&Bs[kk][tn * 8 + 4];
            float av[8] = {a0.x, a0.y, a0.z, a0.w, a1.x, a1.y, a1.z, a1.w};
            float bv[8] = {b0.x, b0.y, b0.z, b0.w, b1.x, b1.y, b1.z, b1.w};
#pragma unroll
            for (int i = 0; i < 8; ++i)
#pragma unroll
                for (int j = 0; j < 8; ++j)
                    acc[i][j] = fmaf(av[i], bv[j], acc[i][j]);
        }
        __syncthreads();
    }
#pragma unroll
    for (int i = 0; i < 8; ++i) {
        float* crow = Cb + (size_t)(m0 + tm * 8 + i) * PP + n0 + tn * 8;
        *(float4*)&crow[0] = make_float4(acc[i][0], acc[i][1], acc[i][2], acc[i][3]);
        *(float4*)&crow[4] = make_float4(acc[i][4], acc[i][5], acc[i][6], acc[i][7]);
    }
}

// ---------------- row norms of k,v -> 1/max(||row||, 1e-12) ----------------
__global__ __launch_bounds__(256) void k_norms(const float* __restrict__ kv,
                                               float* __restrict__ invn) {
    int b = blockIdx.y, r = blockIdx.x;
    const float* row = kv + ((size_t)b * 512 + r) * PP;
    int t = threadIdx.x;
    float s = 0.f;
    for (int p = t * 4; p < PP; p += 1024) {
        float4 v = *(const float4*)&row[p];
        s += v.x * v.x + v.y * v.y + v.z * v.z + v.w * v.w;
    }
#pragma unroll
    for (int o = 32; o > 0; o >>= 1) s += __shfl_down(s, o, 64);
    __shared__ float wsum[4];
    if ((t & 63) == 0) wsum[t >> 6] = s;
    __syncthreads();
    if (t == 0) {
        float tot = wsum[0] + wsum[1] + wsum[2] + wsum[3];
        invn[b * 512 + r] = 1.f / fmaxf(sqrtf(tot), 1e-12f);
    }
}

// ---------------- attention score partials: q . k over 256-p chunks ----------------
__global__ __launch_bounds__(256) void k_attn_part(const float* __restrict__ qp,
                                                   const float* __restrict__ kv,
                                                   float* __restrict__ apart) {
    int ch = blockIdx.x, h = blockIdx.y, b = blockIdx.z;
    int t = threadIdx.x;
    int d = t & 31, cg = t >> 5;
    __shared__ float qs[32][37], ks[32][37];
    float acc[4] = {0.f, 0.f, 0.f, 0.f};
    const float* q0 = qp + ((size_t)b * CC + h * 32) * PP;
    const float* q1 = q0 + (size_t)BB * CC * PP;
    const float* kb = kv + ((size_t)b * 512 + h * 32) * PP;
    int r = t >> 3, cq = (t & 7) * 4;
    for (int po = ch * 256; po < ch * 256 + 256; po += 32) {
        float4 va = *(const float4*)&q0[(size_t)r * PP + po + cq];
        float4 vb = *(const float4*)&q1[(size_t)r * PP + po + cq];
        qs[r][cq + 0] = va.x + vb.x; qs[r][cq + 1] = va.y + vb.y;
        qs[r][cq + 2] = va.z + vb.z; qs[r][cq + 3] = va.w + vb.w;
        float4 vk = *(const float4*)&kb[(size_t)r * PP + po + cq];
        ks[r][cq + 0] = vk.x; ks[r][cq + 1] = vk.y;
        ks[r][cq + 2] = vk.z; ks[r][cq + 3] = vk.w;
        __syncthreads();
#pragma unroll
        for (int pq = 0; pq < 32; ++pq) {
            float kvv = ks[d][pq];
#pragma unroll
            for (int i = 0; i < 4; ++i)
                acc[i] = fmaf(qs[cg * 4 + i][pq], kvv, acc[i]);
        }
        __syncthreads();
    }
    float* ap = apart + (((size_t)(b * 8 + h) * NCH + ch) << 10);
#pragma unroll
    for (int i = 0; i < 4; ++i) ap[(cg * 4 + i) * 32 + d] = acc[i];
}

// ---------------- reduce partials, temp*invnk scale, softmax, *invnv ----------------
__global__ __launch_bounds__(256) void k_attn_fin(const float* __restrict__ apart,
                                                  const float* __restrict__ invn,
                                                  const float* __restrict__ temp,
                                                  float* __restrict__ attns) {
    int h = blockIdx.x, b = blockIdx.y;
    int t = threadIdx.x;
    __shared__ float A[32][33];
    const float* ap = apart + ((size_t)(b * 8 + h) * NCH << 10);
    float th = temp[h];
    for (int e = t; e < 1024; e += 256) {
        float s = 0.f;
        for (int chn = 0; chn < NCH; ++chn) s += ap[chn * 1024 + e];
        int c = e >> 5, d = e & 31;
        A[c][d] = s * th * invn[b * 512 + h * 32 + d];
    }
    __syncthreads();
    if (t < 32) {
        int c = t;
        float m = -INFINITY;
#pragma unroll
        for (int d = 0; d < 32; ++d) m = fmaxf(m, A[c][d]);
        float sum = 0.f;
#pragma unroll
        for (int d = 0; d < 32; ++d) sum += expf(A[c][d] - m);
        float inv = 1.f / sum;
        float* at = attns + ((size_t)(b * 8 + h) << 10) + c * 32;
#pragma unroll
        for (int d = 0; d < 32; ++d)
            at[d] = expf(A[c][d] - m) * inv * invn[b * 512 + 256 + h * 32 + d];
    }
}

// ---------------- mid = attnS @ v (per head, K=32) ----------------
__global__ __launch_bounds__(256) void k_outmid(const float* __restrict__ attns,
                                                const float* __restrict__ kv,
                                                float* __restrict__ mid) {
    int pt = blockIdx.x, h = blockIdx.y, b = blockIdx.z;
    int p0 = pt * 128;
    int t = threadIdx.x;
    int tp = t & 31, tc = t >> 5;
    __shared__ float vs[32][132];
    __shared__ float as[32][33];
    for (int e = t; e < 1024; e += 256)
        as[e >> 5][e & 31] = attns[((size_t)(b * 8 + h) << 10) + e];
    {
        int r = t & 31;
        int c0 = (t >> 5) * 16;
        const float* vrow = kv + ((size_t)b * 512 + 256 + h * 32 + r) * PP + p0;
#pragma unroll
        for (int kq = 0; kq < 4; ++kq)
            *(float4*)&vs[r][c0 + kq * 4] = *(const float4*)&vrow[c0 + kq * 4];
    }
    __syncthreads();
    float acc[4][4];
#pragma unroll
    for (int i = 0; i < 4; ++i)
#pragma unroll
        for (int j = 0; j < 4; ++j) acc[i][j] = 0.f;
#pragma unroll
    for (int d = 0; d < 32; ++d) {
        float4 bv = *(const float4*)&vs[d][tp * 4];
#pragma unroll
        for (int i = 0; i < 4; ++i) {
            float a = as[tc * 4 + i][d];
            acc[i][0] = fmaf(a, bv.x, acc[i][0]);
            acc[i][1] = fmaf(a, bv.y, acc[i][1]);
            acc[i][2] = fmaf(a, bv.z, acc[i][2]);
            acc[i][3] = fmaf(a, bv.w, acc[i][3]);
        }
    }
#pragma unroll
    for (int i = 0; i < 4; ++i) {
        float* mrow = mid + ((size_t)b * CC + h * 32 + tc * 4 + i) * PP + p0 + tp * 4;
        *(float4*)mrow = make_float4(acc[i][0], acc[i][1], acc[i][2], acc[i][3]);
    }
}

extern "C" void kernel_launch(void* const* d_in, const int* in_sizes, int n_in,
                              void* d_out, int out_size, void* d_ws, size_t ws_size,
                              hipStream_t stream) {
    const float* x     = (const float*)d_in[0];
    const float* wp    = (const float*)d_in[1];
    const float* bp    = (const float*)d_in[2];
    const float* wd    = (const float*)d_in[3];
    const float* wqkv  = (const float*)d_in[4];
    const float* temp  = (const float*)d_in[5];
    const float* wproj = (const float*)d_in[6];
    float* out = (float*)d_out;
    float* ws  = (float*)d_ws;

    float* off    = ws + OFF_O;
    int4*  idx4   = (int4*)(ws + IDX_O);
    float4* wgt4  = (float4*)(ws + WGT_O);
    ushort* wt_hi = (ushort*)(ws + WT_O);
    ushort* wt_lo = wt_hi + 9 * 256 * 256;
    float* qpart  = ws + QP_O;
    float* kv     = ws + KV_O;
    float* invn   = ws + INV_O;
    float* apart  = ws + AP_O;
    float* attns  = ws + AT_O;
    float* mid    = ws + MID_O;

    k_prep_wt<<<2304, 256, 0, stream>>>(wd, wt_hi, wt_lo);
    k_pconv<<<dim3(144, BB), 256, 0, stream>>>(x, wp, bp, off);
    k_bilin<<<(BB * 9 * PP + 255) / 256, 256, 0, stream>>>(off, idx4, wgt4);
    k_dconv<<<dim3(144, BB, 2), 256, 0, stream>>>(x, wt_hi, wt_lo, idx4, wgt4, qpart);
    k_gemm<<<dim3(72, 4, BB), 256, 0, stream>>>(wqkv + 256 * 256, x, kv, 512, 256);
    k_norms<<<dim3(512, BB), 256, 0, stream>>>(kv, invn);
    k_attn_part<<<dim3(NCH, HEADS, BB), 256, 0, stream>>>(qpart, kv, apart);
    k_attn_fin<<<dim3(HEADS, BB), 256, 0, stream>>>(apart, invn, temp, attns);
    k_outmid<<<dim3(72, HEADS, BB), 256, 0, stream>>>(attns, kv, mid);
    k_gemm<<<dim3(72, 2, BB), 256, 0, stream>>>(wproj, mid, out, 256, 256);
}

// Round 3
// 448.378 us; speedup vs baseline: 2.7631x; 1.4501x over previous
//
#include <hip/hip_runtime.h>
#include <math.h>

#define BB 2
#define CC 256
#define HW 96
#define PP 9216
#define KO 18
#define HEADS 8
#define NCH 36

typedef short bf16x8 __attribute__((ext_vector_type(8)));
typedef float f32x4 __attribute__((ext_vector_type(4)));

// ws layout (float offsets)
#define OFF_O   0UL          // 2*18*9216 = 331776
#define IDX_O   331776UL     // int4 table 663552
#define WGT_O   995328UL     // float4 table 663552
#define WT2_O   1658880UL    // wt2 hi+lo (589824 ushorts each) = 589824 floats
#define WP2_O   2248704UL    // wp2 hi+lo (73728 ushorts each) = 73728 floats
#define QP_O    2322432UL    // qpart (9437184 fl); aliases ppart & mid (sequential lifetimes)
#define KV_O    11759616UL   // k,v 2*512*9216 = 9437184
#define INV_O   21196800UL   // 1024
#define AP_O    21197824UL   // 589824
#define AT_O    21787648UL   // 16384

__device__ __forceinline__ ushort f2bf_rne(float f) {
    unsigned u = __float_as_uint(f);
    unsigned r = (u + 0x7FFFu + ((u >> 16) & 1u)) >> 16;
    return (ushort)r;
}
__device__ __forceinline__ float bf2f(ushort h) {
    return __uint_as_float(((unsigned)h) << 16);
}

// ---- prep: wd[o][c][kk] -> wt2 hi/lo [kk][cs][u]*8, u = (o&15)*4 + lhi + (o>>4)*64
__global__ __launch_bounds__(256) void k_prep_wt(const float* __restrict__ wd,
                                                 ushort* __restrict__ h,
                                                 ushort* __restrict__ lo) {
    int tid = blockIdx.x * 256 + threadIdx.x;
    if (tid >= 9 * 8 * 1024 * 8) return;
    int e = tid & 7;
    int u = (tid >> 3) & 1023;
    int cs = (tid >> 13) & 7;
    int kk = tid >> 16;
    int oh = u >> 6, rem = u & 63;
    int lrow = rem >> 2, lhi = rem & 3;
    int o = oh * 16 + lrow;
    int c = cs * 32 + lhi * 8 + e;
    float v = wd[o * 2304 + c * 9 + kk];
    ushort hh = f2bf_rne(v);
    h[tid] = hh;
    lo[tid] = f2bf_rne(v - bf2f(hh));
}

// ---- prep: wp[o][c][kk] (o<18, pad to 32) -> wp2 hi/lo [kk][cs][u]*8, u = lrow*4+lhi+mf*64
__global__ __launch_bounds__(256) void k_prep_wp(const float* __restrict__ wp,
                                                 ushort* __restrict__ h,
                                                 ushort* __restrict__ lo) {
    int tid = blockIdx.x * 256 + threadIdx.x;
    if (tid >= 9 * 8 * 128 * 8) return;
    int e = tid & 7;
    int u = (tid >> 3) & 127;
    int cs = (tid >> 10) & 7;
    int kk = tid >> 13;
    int mf = u >> 6, rem = u & 63;
    int lrow = rem >> 2, lhi = rem & 3;
    int o = mf * 16 + lrow;
    int c = cs * 32 + lhi * 8 + e;
    float v = (o < KO) ? wp[(o * 256 + c) * 9 + kk] : 0.f;
    ushort hh = f2bf_rne(v);
    h[tid] = hh;
    lo[tid] = f2bf_rne(v - bf2f(hh));
}

// ---- pconv as MFMA implicit-GEMM, K-split 4 (64 c each), M=32(pad of 18), N=64 ----
__global__ __launch_bounds__(256) void k_pconv(const float* __restrict__ x,
                                               const ushort* __restrict__ wp2h,
                                               const ushort* __restrict__ wp2l,
                                               float* __restrict__ ppart) {
    int b = blockIdx.y, s = blockIdx.z;
    int p0 = blockIdx.x * 64;
    int t = threadIdx.x;
    int l = t & 63, w = t >> 6;
    int lrow = l & 15, lhi = l >> 4;
    int p = t & 63, cg = t >> 6;
    __shared__ __align__(16) ushort Sh[64 * 40];
    __shared__ __align__(16) ushort Sl[64 * 40];
    f32x4 acc[2];
    acc[0] = (f32x4)0.f; acc[1] = (f32x4)0.f;
    const float* xb = x + (size_t)b * CC * PP;
    int pix = p0 + p;
    int i_ = pix / 96, j_ = pix % 96;
    for (int kk = 0; kk < 9; ++kk) {
        int di = kk / 3 - 1, dj = kk % 3 - 1;
        bool vOK = ((unsigned)(i_ + di) < 96u) && ((unsigned)(j_ + dj) < 96u);
        int poff = pix + di * 96 + dj;
#pragma unroll 1
        for (int cs = 0; cs < 2; ++cs) {
            int csg = s * 2 + cs;
            __syncthreads();
            bf16x8 ah[2], al[2];
#pragma unroll
            for (int mf = 0; mf < 2; ++mf) {
                size_t gi = (((size_t)(kk * 8 + csg)) * 128 + (lrow * 4 + lhi + mf * 64)) * 8;
                ah[mf] = *(const bf16x8*)&wp2h[gi];
                al[mf] = *(const bf16x8*)&wp2l[gi];
            }
            const float* xc0 = xb + (size_t)(csg * 32 + cg * 8) * PP;
            bf16x8 vh, vl;
#pragma unroll
            for (int i = 0; i < 8; ++i) {
                float v = vOK ? xc0[(size_t)i * PP + poff] : 0.f;
                ushort hh = f2bf_rne(v);
                vh[i] = (short)hh;
                vl[i] = (short)f2bf_rne(v - bf2f(hh));
            }
            *(bf16x8*)&Sh[p * 40 + cg * 8] = vh;
            *(bf16x8*)&Sl[p * 40 + cg * 8] = vl;
            __syncthreads();
            bf16x8 Bh = *(const bf16x8*)&Sh[(w * 16 + lrow) * 40 + lhi * 8];
            bf16x8 Bl = *(const bf16x8*)&Sl[(w * 16 + lrow) * 40 + lhi * 8];
#pragma unroll
            for (int mf = 0; mf < 2; ++mf) {
                acc[mf] = __builtin_amdgcn_mfma_f32_16x16x32_bf16(ah[mf], Bh, acc[mf], 0, 0, 0);
                acc[mf] = __builtin_amdgcn_mfma_f32_16x16x32_bf16(ah[mf], Bl, acc[mf], 0, 0, 0);
                acc[mf] = __builtin_amdgcn_mfma_f32_16x16x32_bf16(al[mf], Bh, acc[mf], 0, 0, 0);
            }
        }
    }
    float* pr = ppart + ((size_t)(s * BB + b) * 32) * PP;
#pragma unroll
    for (int mf = 0; mf < 2; ++mf)
#pragma unroll
        for (int j = 0; j < 4; ++j)
            pr[(size_t)(mf * 16 + lhi * 4 + j) * PP + p0 + w * 16 + lrow] = acc[mf][j];
}

// ---- reduce pconv partials + bias -> off[b][18][9216] ----
__global__ __launch_bounds__(256) void k_pred(const float* __restrict__ pp,
                                              const float* __restrict__ bp,
                                              float* __restrict__ off) {
    int idx = blockIdx.x * 256 + threadIdx.x;
    if (idx >= BB * KO * PP) return;
    int p = idx % PP;
    int t2 = idx / PP;
    int o = t2 % KO, b = t2 / KO;
    float s = bp[o];
#pragma unroll
    for (int k = 0; k < 4; ++k) s += pp[((size_t)(k * BB + b) * 32 + o) * PP + p];
    off[idx] = s;
}

// ---- bilinear table: always-valid index, zero weight if OOB ----
__global__ __launch_bounds__(256) void k_bilin(const float* __restrict__ off,
                                               int4* __restrict__ idx4,
                                               float4* __restrict__ wgt4) {
    int idx = blockIdx.x * 256 + threadIdx.x;
    if (idx >= BB * 9 * PP) return;
    int p = idx % PP;
    int bn = idx / PP;
    int n = bn % 9, b = bn / 9;
    int i = p / 96, j = p % 96;
    float ox = off[((size_t)b * KO + n) * PP + p];
    float oy = off[((size_t)b * KO + 9 + n) * PP + p];
    float px = ox + (float)(n / 3 - 1) + (float)(i + 1);
    float py = oy + (float)(n % 3 - 1) + (float)(j + 1);
    float fx = floorf(px), fy = floorf(py);
    float qltx = fminf(fmaxf(fx, 0.f), 97.f);
    float qlty = fminf(fmaxf(fy, 0.f), 97.f);
    float qrbx = fminf(fmaxf(fx + 1.f, 0.f), 97.f);
    float qrby = fminf(fmaxf(fy + 1.f, 0.f), 97.f);
    float pxc = fminf(fmaxf(px, 0.f), 97.f);
    float pyc = fminf(fmaxf(py, 0.f), 97.f);
    float glt = (1.f + (qltx - pxc)) * (1.f + (qlty - pyc));
    float grb = (1.f - (qrbx - pxc)) * (1.f - (qrby - pyc));
    float glb = (1.f + (qltx - pxc)) * (1.f - (qrby - pyc));
    float grt = (1.f - (qrbx - pxc)) * (1.f + (qlty - pyc));
    int x0 = (int)qltx - 1, y0 = (int)qlty - 1;
    int x1 = (int)qrbx - 1, y1 = (int)qrby - 1;
    bool vlt = (x0 >= 0 && x0 < 96 && y0 >= 0 && y0 < 96);
    bool vrb = (x1 >= 0 && x1 < 96 && y1 >= 0 && y1 < 96);
    bool vlb = (x0 >= 0 && x0 < 96 && y1 >= 0 && y1 < 96);
    bool vrt = (x1 >= 0 && x1 < 96 && y0 >= 0 && y0 < 96);
    int4 id;
    id.x = vlt ? x0 * 96 + y0 : 0;
    id.y = vrb ? x1 * 96 + y1 : 0;
    id.z = vlb ? x0 * 96 + y1 : 0;
    id.w = vrt ? x1 * 96 + y0 : 0;
    idx4[idx] = id;
    wgt4[idx] = make_float4(vlt ? glt : 0.f, vrb ? grb : 0.f,
                            vlb ? glb : 0.f, vrt ? grt : 0.f);
}

// ---- deformable conv MFMA: BM=256, BN=64, c-split halves; A direct-to-register ----
__global__ __launch_bounds__(256) void k_dconv(const float* __restrict__ x,
                                               const ushort* __restrict__ wt2h,
                                               const ushort* __restrict__ wt2l,
                                               const int4* __restrict__ idx4,
                                               const float4* __restrict__ wgt4,
                                               float* __restrict__ qpart) {
    int b = blockIdx.y;
    int half = blockIdx.z;
    int p0 = blockIdx.x * 64;
    int t = threadIdx.x;
    int l = t & 63, w = t >> 6;
    int lrow = l & 15, lhi = l >> 4;
    int obase = w * 64;
    int p = t & 63, cg = t >> 6;

    __shared__ __align__(16) ushort Sh[64 * 40];
    __shared__ __align__(16) ushort Sl[64 * 40];

    f32x4 acc[4][4];
#pragma unroll
    for (int mf = 0; mf < 4; ++mf)
#pragma unroll
        for (int nf = 0; nf < 4; ++nf) acc[mf][nf] = (f32x4)0.f;

    const float* xb = x + (size_t)b * CC * PP;

    for (int kk = 0; kk < 9; ++kk) {
        size_t tb = ((size_t)b * 9 + kk) * PP + p0 + p;
        int4 id = idx4[tb];
        float4 g4 = wgt4[tb];
#pragma unroll 1
        for (int cs = 0; cs < 4; ++cs) {
            int csg = half * 4 + cs;
            __syncthreads();   // previous step's S reads done
            // A fragments direct from global (L2-resident, coalesced permuted layout)
            bf16x8 ah[4], al[4];
#pragma unroll
            for (int mf = 0; mf < 4; ++mf) {
                size_t gi = (((size_t)(kk * 8 + csg)) * 1024 + (lrow * 4 + lhi + (w * 4 + mf) * 64)) * 8;
                ah[mf] = *(const bf16x8*)&wt2h[gi];
                al[mf] = *(const bf16x8*)&wt2l[gi];
            }
            // gather-generate S tile (8 c's per thread, one pixel)
            const float* xp0 = xb + (size_t)(csg * 32 + cg * 8) * PP;
            bf16x8 vh, vl;
#pragma unroll
            for (int i = 0; i < 8; ++i) {
                const float* xc = xp0 + (size_t)i * PP;
                float v = g4.x * xc[id.x];
                v = fmaf(g4.y, xc[id.y], v);
                v = fmaf(g4.z, xc[id.z], v);
                v = fmaf(g4.w, xc[id.w], v);
                ushort hh = f2bf_rne(v);
                vh[i] = (short)hh;
                vl[i] = (short)f2bf_rne(v - bf2f(hh));
            }
            *(bf16x8*)&Sh[p * 40 + cg * 8] = vh;
            *(bf16x8*)&Sl[p * 40 + cg * 8] = vl;
            __syncthreads();   // S visible
            bf16x8 Bh4[4], Bl4[4];
#pragma unroll
            for (int nf = 0; nf < 4; ++nf) {
                Bh4[nf] = *(const bf16x8*)&Sh[(nf * 16 + lrow) * 40 + lhi * 8];
                Bl4[nf] = *(const bf16x8*)&Sl[(nf * 16 + lrow) * 40 + lhi * 8];
            }
#pragma unroll
            for (int mf = 0; mf < 4; ++mf) {
#pragma unroll
                for (int nf = 0; nf < 4; ++nf) {
                    acc[mf][nf] = __builtin_amdgcn_mfma_f32_16x16x32_bf16(ah[mf], Bh4[nf], acc[mf][nf], 0, 0, 0);
                    acc[mf][nf] = __builtin_amdgcn_mfma_f32_16x16x32_bf16(ah[mf], Bl4[nf], acc[mf][nf], 0, 0, 0);
                    acc[mf][nf] = __builtin_amdgcn_mfma_f32_16x16x32_bf16(al[mf], Bh4[nf], acc[mf][nf], 0, 0, 0);
                }
            }
        }
    }
    float* qh = qpart + (size_t)half * BB * CC * PP + (size_t)b * CC * PP;
#pragma unroll
    for (int mf = 0; mf < 4; ++mf)
#pragma unroll
        for (int nf = 0; nf < 4; ++nf)
#pragma unroll
            for (int j = 0; j < 4; ++j)
                qh[(size_t)(obase + mf * 16 + lhi * 4 + j) * PP + p0 + nf * 16 + lrow] =
                    acc[mf][nf][j];
}

// ---- generic fp32 GEMM: C[b] = A(MxKc) * B[b](KcxPP) ----
__global__ __launch_bounds__(256) void k_gemm(const float* __restrict__ A,
                                              const float* __restrict__ Bsrc,
                                              float* __restrict__ Cdst,
                                              int M, int Kc) {
    int b = blockIdx.z;
    int n0 = blockIdx.x * 128;
    int m0 = blockIdx.y * 128;
    const float* Bb = Bsrc + (size_t)b * Kc * PP;
    float* Cb = Cdst + (size_t)b * M * PP;
    __shared__ float As[16][132];
    __shared__ float Bs[16][132];
    int t = threadIdx.x;
    int tm = t & 15, tn = t >> 4;
    float acc[8][8];
#pragma unroll
    for (int a = 0; a < 8; ++a)
#pragma unroll
        for (int c = 0; c < 8; ++c) acc[a][c] = 0.f;

    for (int k0 = 0; k0 < Kc; k0 += 16) {
#pragma unroll
        for (int r = 0; r < 2; ++r) {
            int m = (t >> 2) + r * 64;
            int kq = (t & 3) * 4;
            float4 va = *(const float4*)&A[(size_t)(m0 + m) * Kc + k0 + kq];
            As[kq + 0][m] = va.x; As[kq + 1][m] = va.y;
            As[kq + 2][m] = va.z; As[kq + 3][m] = va.w;
        }
#pragma unroll
        for (int r = 0; r < 2; ++r) {
            int kB = t >> 4;
            int nq = (t & 15) * 8 + r * 4;
            *(float4*)&Bs[kB][nq] = *(const float4*)&Bb[(size_t)(k0 + kB) * PP + n0 + nq];
        }
        __syncthreads();
#pragma unroll
        for (int kk = 0; kk < 16; ++kk) {
            const float4 a0 = *(const float4*)&As[kk][tm * 8];
            const float4 a1 = *(const float4*)&As[kk][tm * 8 + 4];
            const float4 b0 = *(const float4*)&Bs[kk][tn * 8];
            const float4 b1 = *(const float4*)&Bs[kk][tn * 8 + 4];
            float av[8] = {a0.x, a0.y, a0.z, a0.w, a1.x, a1.y, a1.z, a1.w};
            float bv[8] = {b0.x, b0.y, b0.z, b0.w, b1.x, b1.y, b1.z, b1.w};
#pragma unroll
            for (int i = 0; i < 8; ++i)
#pragma unroll
                for (int j = 0; j < 8; ++j)
                    acc[i][j] = fmaf(av[i], bv[j], acc[i][j]);
        }
        __syncthreads();
    }
#pragma unroll
    for (int i = 0; i < 8; ++i) {
        float* crow = Cb + (size_t)(m0 + tm * 8 + i) * PP + n0 + tn * 8;
        *(float4*)&crow[0] = make_float4(acc[i][0], acc[i][1], acc[i][2], acc[i][3]);
        *(float4*)&crow[4] = make_float4(acc[i][4], acc[i][5], acc[i][6], acc[i][7]);
    }
}

// ---- row norms of k,v -> 1/max(||row||, 1e-12) ----
__global__ __launch_bounds__(256) void k_norms(const float* __restrict__ kv,
                                               float* __restrict__ invn) {
    int b = blockIdx.y, r = blockIdx.x;
    const float* row = kv + ((size_t)b * 512 + r) * PP;
    int t = threadIdx.x;
    float s = 0.f;
    for (int p = t * 4; p < PP; p += 1024) {
        float4 v = *(const float4*)&row[p];
        s += v.x * v.x + v.y * v.y + v.z * v.z + v.w * v.w;
    }
#pragma unroll
    for (int o = 32; o > 0; o >>= 1) s += __shfl_down(s, o, 64);
    __shared__ float wsum[4];
    if ((t & 63) == 0) wsum[t >> 6] = s;
    __syncthreads();
    if (t == 0) {
        float tot = wsum[0] + wsum[1] + wsum[2] + wsum[3];
        invn[b * 512 + r] = 1.f / fmaxf(sqrtf(tot), 1e-12f);
    }
}

// ---- attention score partials: q . k over 256-p chunks ----
__global__ __launch_bounds__(256) void k_attn_part(const float* __restrict__ qp,
                                                   const float* __restrict__ kv,
                                                   float* __restrict__ apart) {
    int ch = blockIdx.x, h = blockIdx.y, b = blockIdx.z;
    int t = threadIdx.x;
    int d = t & 31, cg = t >> 5;
    __shared__ float qs[32][37], ks[32][37];
    float acc[4] = {0.f, 0.f, 0.f, 0.f};
    const float* q0 = qp + ((size_t)b * CC + h * 32) * PP;
    const float* q1 = q0 + (size_t)BB * CC * PP;
    const float* kb = kv + ((size_t)b * 512 + h * 32) * PP;
    int r = t >> 3, cq = (t & 7) * 4;
    for (int po = ch * 256; po < ch * 256 + 256; po += 32) {
        float4 va = *(const float4*)&q0[(size_t)r * PP + po + cq];
        float4 vb = *(const float4*)&q1[(size_t)r * PP + po + cq];
        qs[r][cq + 0] = va.x + vb.x; qs[r][cq + 1] = va.y + vb.y;
        qs[r][cq + 2] = va.z + vb.z; qs[r][cq + 3] = va.w + vb.w;
        float4 vk = *(const float4*)&kb[(size_t)r * PP + po + cq];
        ks[r][cq + 0] = vk.x; ks[r][cq + 1] = vk.y;
        ks[r][cq + 2] = vk.z; ks[r][cq + 3] = vk.w;
        __syncthreads();
#pragma unroll
        for (int pq = 0; pq < 32; ++pq) {
            float kvv = ks[d][pq];
#pragma unroll
            for (int i = 0; i < 4; ++i)
                acc[i] = fmaf(qs[cg * 4 + i][pq], kvv, acc[i]);
        }
        __syncthreads();
    }
    float* ap = apart + (((size_t)(b * 8 + h) * NCH + ch) << 10);
#pragma unroll
    for (int i = 0; i < 4; ++i) ap[(cg * 4 + i) * 32 + d] = acc[i];
}

// ---- reduce partials, temp*invnk scale, softmax, *invnv ----
__global__ __launch_bounds__(256) void k_attn_fin(const float* __restrict__ apart,
                                                  const float* __restrict__ invn,
                                                  const float* __restrict__ temp,
                                                  float* __restrict__ attns) {
    int h = blockIdx.x, b = blockIdx.y;
    int t = threadIdx.x;
    __shared__ float A[32][33];
    const float* ap = apart + ((size_t)(b * 8 + h) * NCH << 10);
    float th = temp[h];
    for (int e = t; e < 1024; e += 256) {
        float s = 0.f;
        for (int chn = 0; chn < NCH; ++chn) s += ap[chn * 1024 + e];
        int c = e >> 5, d = e & 31;
        A[c][d] = s * th * invn[b * 512 + h * 32 + d];
    }
    __syncthreads();
    if (t < 32) {
        int c = t;
        float m = -INFINITY;
#pragma unroll
        for (int d = 0; d < 32; ++d) m = fmaxf(m, A[c][d]);
        float sum = 0.f;
#pragma unroll
        for (int d = 0; d < 32; ++d) sum += expf(A[c][d] - m);
        float inv = 1.f / sum;
        float* at = attns + ((size_t)(b * 8 + h) << 10) + c * 32;
#pragma unroll
        for (int d = 0; d < 32; ++d)
            at[d] = expf(A[c][d] - m) * inv * invn[b * 512 + 256 + h * 32 + d];
    }
}

// ---- mid = attnS @ v (per head, K=32) ----
__global__ __launch_bounds__(256) void k_outmid(const float* __restrict__ attns,
                                                const float* __restrict__ kv,
                                                float* __restrict__ mid) {
    int pt = blockIdx.x, h = blockIdx.y, b = blockIdx.z;
    int p0 = pt * 128;
    int t = threadIdx.x;
    int tp = t & 31, tc = t >> 5;
    __shared__ float vs[32][132];
    __shared__ float as[32][33];
    for (int e = t; e < 1024; e += 256)
        as[e >> 5][e & 31] = attns[((size_t)(b * 8 + h) << 10) + e];
    {
        int r = t & 31;
        int c0 = (t >> 5) * 16;
        const float* vrow = kv + ((size_t)b * 512 + 256 + h * 32 + r) * PP + p0;
#pragma unroll
        for (int kq = 0; kq < 4; ++kq)
            *(float4*)&vs[r][c0 + kq * 4] = *(const float4*)&vrow[c0 + kq * 4];
    }
    __syncthreads();
    float acc[4][4];
#pragma unroll
    for (int i = 0; i < 4; ++i)
#pragma unroll
        for (int j = 0; j < 4; ++j) acc[i][j] = 0.f;
#pragma unroll
    for (int d = 0; d < 32; ++d) {
        float4 bv = *(const float4*)&vs[d][tp * 4];
#pragma unroll
        for (int i = 0; i < 4; ++i) {
            float a = as[tc * 4 + i][d];
            acc[i][0] = fmaf(a, bv.x, acc[i][0]);
            acc[i][1] = fmaf(a, bv.y, acc[i][1]);
            acc[i][2] = fmaf(a, bv.z, acc[i][2]);
            acc[i][3] = fmaf(a, bv.w, acc[i][3]);
        }
    }
#pragma unroll
    for (int i = 0; i < 4; ++i) {
        float* mrow = mid + ((size_t)b * CC + h * 32 + tc * 4 + i) * PP + p0 + tp * 4;
        *(float4*)mrow = make_float4(acc[i][0], acc[i][1], acc[i][2], acc[i][3]);
    }
}

extern "C" void kernel_launch(void* const* d_in, const int* in_sizes, int n_in,
                              void* d_out, int out_size, void* d_ws, size_t ws_size,
                              hipStream_t stream) {
    const float* x     = (const float*)d_in[0];
    const float* wp    = (const float*)d_in[1];
    const float* bp    = (const float*)d_in[2];
    const float* wd    = (const float*)d_in[3];
    const float* wqkv  = (const float*)d_in[4];
    const float* temp  = (const float*)d_in[5];
    const float* wproj = (const float*)d_in[6];
    float* out = (float*)d_out;
    float* ws  = (float*)d_ws;

    float* off    = ws + OFF_O;
    int4*  idx4   = (int4*)(ws + IDX_O);
    float4* wgt4  = (float4*)(ws + WGT_O);
    ushort* wt2h  = (ushort*)(ws + WT2_O);
    ushort* wt2l  = wt2h + 9 * 8 * 1024 * 8;
    ushort* wp2h  = (ushort*)(ws + WP2_O);
    ushort* wp2l  = wp2h + 9 * 8 * 128 * 8;
    float* qpart  = ws + QP_O;   // aliases ppart and mid (sequential lifetimes)
    float* ppart  = ws + QP_O;
    float* mid    = ws + QP_O;
    float* kv     = ws + KV_O;
    float* invn   = ws + INV_O;
    float* apart  = ws + AP_O;
    float* attns  = ws + AT_O;

    k_prep_wt<<<2304, 256, 0, stream>>>(wd, wt2h, wt2l);
    k_prep_wp<<<288, 256, 0, stream>>>(wp, wp2h, wp2l);
    k_pconv<<<dim3(144, BB, 4), 256, 0, stream>>>(x, wp2h, wp2l, ppart);
    k_pred<<<(BB * KO * PP + 255) / 256, 256, 0, stream>>>(ppart, bp, off);
    k_bilin<<<(BB * 9 * PP + 255) / 256, 256, 0, stream>>>(off, idx4, wgt4);
    k_dconv<<<dim3(144, BB, 2), 256, 0, stream>>>(x, wt2h, wt2l, idx4, wgt4, qpart);
    k_gemm<<<dim3(72, 4, BB), 256, 0, stream>>>(wqkv + 256 * 256, x, kv, 512, 256);
    k_norms<<<dim3(512, BB), 256, 0, stream>>>(kv, invn);
    k_attn_part<<<dim3(NCH, HEADS, BB), 256, 0, stream>>>(qpart, kv, apart);
    k_attn_fin<<<dim3(HEADS, BB), 256, 0, stream>>>(apart, invn, temp, attns);
    k_outmid<<<dim3(72, HEADS, BB), 256, 0, stream>>>(attns, kv, mid);
    k_gemm<<<dim3(72, 2, BB), 256, 0, stream>>>(wproj, mid, out, 256, 256);
}

// Round 4
// 343.634 us; speedup vs baseline: 3.6053x; 1.3048x over previous
//
#include <hip/hip_runtime.h>
#include <math.h>

#define BB 2
#define CC 256
#define HW 96
#define PP 9216
#define KO 18
#define HEADS 8
#define NCH 36

typedef short bf16x8 __attribute__((ext_vector_type(8)));
typedef float f32x4 __attribute__((ext_vector_type(4)));

// ws layout (float offsets)
#define OFF_O   0UL          // 2*18*9216 = 331776
#define IDX_O   331776UL     // int4 table 663552
#define WGT_O   995328UL     // float4 table 663552
#define WT2_O   1658880UL    // wt2 hi+lo (589824 ushorts each) = 589824 floats
#define WP2_O   2248704UL    // wp2 hi+lo (73728 ushorts each) = 73728 floats
#define WQ2_O   2322432UL    // wq2 hi+lo (131072 ushorts each) = 131072 floats
#define WPR2_O  2453504UL    // wpr2 hi+lo (65536 ushorts each) = 65536 floats
#define QP_O    2519040UL    // qpart 9437184; aliases ppart & mid (sequential lifetimes)
#define KV_O    11956224UL   // k,v 2*512*9216 = 9437184
#define INV_O   21393408UL   // 1024
#define AP_O    21394432UL   // 589824
#define AT_O    21984256UL   // 16384

__device__ __forceinline__ ushort f2bf_rne(float f) {
    unsigned u = __float_as_uint(f);
    unsigned r = (u + 0x7FFFu + ((u >> 16) & 1u)) >> 16;
    return (ushort)r;
}
__device__ __forceinline__ float bf2f(ushort h) {
    return __uint_as_float(((unsigned)h) << 16);
}

// ---- prep: wd[o][c][kk] -> wt2 hi/lo [kk][csg][u]*8 ----
__global__ __launch_bounds__(256) void k_prep_wt(const float* __restrict__ wd,
                                                 ushort* __restrict__ h,
                                                 ushort* __restrict__ lo) {
    int tid = blockIdx.x * 256 + threadIdx.x;
    if (tid >= 9 * 8 * 1024 * 8) return;
    int e = tid & 7;
    int u = (tid >> 3) & 1023;
    int cs = (tid >> 13) & 7;
    int kk = tid >> 16;
    int oh = u >> 6, rem = u & 63;
    int lrow = rem >> 2, lhi = rem & 3;
    int o = oh * 16 + lrow;
    int c = cs * 32 + lhi * 8 + e;
    float v = wd[o * 2304 + c * 9 + kk];
    ushort hh = f2bf_rne(v);
    h[tid] = hh;
    lo[tid] = f2bf_rne(v - bf2f(hh));
}

// ---- prep: wp[o][c][kk] (o<18, pad to 32) -> wp2 hi/lo [kk][csg][u]*8 ----
__global__ __launch_bounds__(256) void k_prep_wp(const float* __restrict__ wp,
                                                 ushort* __restrict__ h,
                                                 ushort* __restrict__ lo) {
    int tid = blockIdx.x * 256 + threadIdx.x;
    if (tid >= 9 * 8 * 128 * 8) return;
    int e = tid & 7;
    int u = (tid >> 3) & 127;
    int cs = (tid >> 10) & 7;
    int kk = tid >> 13;
    int mf = u >> 6, rem = u & 63;
    int lrow = rem >> 2, lhi = rem & 3;
    int o = mf * 16 + lrow;
    int c = cs * 32 + lhi * 8 + e;
    float v = (o < KO) ? wp[(o * 256 + c) * 9 + kk] : 0.f;
    ushort hh = f2bf_rne(v);
    h[tid] = hh;
    lo[tid] = f2bf_rne(v - bf2f(hh));
}

// ---- prep generic weight W[M][256] (row-major) -> [mt][csg][u]*8 hi/lo ----
__global__ __launch_bounds__(256) void k_prep_w(const float* __restrict__ W,
                                                ushort* __restrict__ h,
                                                ushort* __restrict__ lo,
                                                int total) {
    int tid = blockIdx.x * 256 + threadIdx.x;
    if (tid >= total) return;
    int e = tid & 7;
    int u = (tid >> 3) & 1023;
    int csg = (tid >> 13) & 7;
    int mt = tid >> 16;
    int rem = u & 63;
    int lrow = rem >> 2, lhi = rem & 3;
    int o = mt * 256 + (u >> 6) * 16 + lrow;
    int c = csg * 32 + lhi * 8 + e;
    float v = W[o * 256 + c];
    ushort hh = f2bf_rne(v);
    h[tid] = hh;
    lo[tid] = f2bf_rne(v - bf2f(hh));
}

// ---- pconv MFMA, XCD-swizzled 1D grid of 1152: xcd owns one (b,ksplit) ----
__global__ __launch_bounds__(256) void k_pconv(const float* __restrict__ x,
                                               const ushort* __restrict__ wp2h,
                                               const ushort* __restrict__ wp2l,
                                               float* __restrict__ ppart) {
    int s = blockIdx.x;
    int xcd = s & 7;
    int b = xcd & 1, ks = xcd >> 1;
    int p0 = (s >> 3) * 64;
    int t = threadIdx.x;
    int l = t & 63, w = t >> 6;
    int lrow = l & 15, lhi = l >> 4;
    int p = t & 63, cg = t >> 6;
    __shared__ __align__(16) ushort Sh[64 * 40];
    __shared__ __align__(16) ushort Sl[64 * 40];
    f32x4 acc[2];
    acc[0] = (f32x4)0.f; acc[1] = (f32x4)0.f;
    const float* xb = x + (size_t)b * CC * PP;
    int pix = p0 + p;
    int i_ = pix / 96, j_ = pix % 96;
#pragma unroll 1
    for (int cs = 0; cs < 2; ++cs) {
        int csg = ks * 2 + cs;
        const float* xc0 = xb + (size_t)(csg * 32 + cg * 8) * PP;
#pragma unroll 1
        for (int kk = 0; kk < 9; ++kk) {
            int di = kk / 3 - 1, dj = kk % 3 - 1;
            bool vOK = ((unsigned)(i_ + di) < 96u) && ((unsigned)(j_ + dj) < 96u);
            int poff = pix + di * 96 + dj;
            __syncthreads();
            bf16x8 ah[2], al[2];
#pragma unroll
            for (int mf = 0; mf < 2; ++mf) {
                size_t gi = (((size_t)(kk * 8 + csg)) * 128 + (lrow * 4 + lhi + mf * 64)) * 8;
                ah[mf] = *(const bf16x8*)&wp2h[gi];
                al[mf] = *(const bf16x8*)&wp2l[gi];
            }
            bf16x8 vh, vl;
#pragma unroll
            for (int i = 0; i < 8; ++i) {
                float v = vOK ? xc0[(size_t)i * PP + poff] : 0.f;
                ushort hh = f2bf_rne(v);
                vh[i] = (short)hh;
                vl[i] = (short)f2bf_rne(v - bf2f(hh));
            }
            *(bf16x8*)&Sh[p * 40 + cg * 8] = vh;
            *(bf16x8*)&Sl[p * 40 + cg * 8] = vl;
            __syncthreads();
            bf16x8 Bh = *(const bf16x8*)&Sh[(w * 16 + lrow) * 40 + lhi * 8];
            bf16x8 Bl = *(const bf16x8*)&Sl[(w * 16 + lrow) * 40 + lhi * 8];
#pragma unroll
            for (int mf = 0; mf < 2; ++mf) {
                acc[mf] = __builtin_amdgcn_mfma_f32_16x16x32_bf16(ah[mf], Bh, acc[mf], 0, 0, 0);
                acc[mf] = __builtin_amdgcn_mfma_f32_16x16x32_bf16(ah[mf], Bl, acc[mf], 0, 0, 0);
                acc[mf] = __builtin_amdgcn_mfma_f32_16x16x32_bf16(al[mf], Bh, acc[mf], 0, 0, 0);
            }
        }
    }
    float* pr = ppart + ((size_t)(ks * BB + b) * 32) * PP;
#pragma unroll
    for (int mf = 0; mf < 2; ++mf)
#pragma unroll
        for (int j = 0; j < 4; ++j)
            pr[(size_t)(mf * 16 + lhi * 4 + j) * PP + p0 + w * 16 + lrow] = acc[mf][j];
}

// ---- reduce pconv partials + bias -> off[b][18][9216] ----
__global__ __launch_bounds__(256) void k_pred(const float* __restrict__ pp,
                                              const float* __restrict__ bp,
                                              float* __restrict__ off) {
    int idx = blockIdx.x * 256 + threadIdx.x;
    if (idx >= BB * KO * PP) return;
    int p = idx % PP;
    int t2 = idx / PP;
    int o = t2 % KO, b = t2 / KO;
    float s = bp[o];
#pragma unroll
    for (int k = 0; k < 4; ++k) s += pp[((size_t)(k * BB + b) * 32 + o) * PP + p];
    off[idx] = s;
}

// ---- bilinear table: always-valid index, zero weight if OOB ----
__global__ __launch_bounds__(256) void k_bilin(const float* __restrict__ off,
                                               int4* __restrict__ idx4,
                                               float4* __restrict__ wgt4) {
    int idx = blockIdx.x * 256 + threadIdx.x;
    if (idx >= BB * 9 * PP) return;
    int p = idx % PP;
    int bn = idx / PP;
    int n = bn % 9, b = bn / 9;
    int i = p / 96, j = p % 96;
    float ox = off[((size_t)b * KO + n) * PP + p];
    float oy = off[((size_t)b * KO + 9 + n) * PP + p];
    float px = ox + (float)(n / 3 - 1) + (float)(i + 1);
    float py = oy + (float)(n % 3 - 1) + (float)(j + 1);
    float fx = floorf(px), fy = floorf(py);
    float qltx = fminf(fmaxf(fx, 0.f), 97.f);
    float qlty = fminf(fmaxf(fy, 0.f), 97.f);
    float qrbx = fminf(fmaxf(fx + 1.f, 0.f), 97.f);
    float qrby = fminf(fmaxf(fy + 1.f, 0.f), 97.f);
    float pxc = fminf(fmaxf(px, 0.f), 97.f);
    float pyc = fminf(fmaxf(py, 0.f), 97.f);
    float glt = (1.f + (qltx - pxc)) * (1.f + (qlty - pyc));
    float grb = (1.f - (qrbx - pxc)) * (1.f - (qrby - pyc));
    float glb = (1.f + (qltx - pxc)) * (1.f - (qrby - pyc));
    float grt = (1.f - (qrbx - pxc)) * (1.f + (qlty - pyc));
    int x0 = (int)qltx - 1, y0 = (int)qlty - 1;
    int x1 = (int)qrbx - 1, y1 = (int)qrby - 1;
    bool vlt = (x0 >= 0 && x0 < 96 && y0 >= 0 && y0 < 96);
    bool vrb = (x1 >= 0 && x1 < 96 && y1 >= 0 && y1 < 96);
    bool vlb = (x0 >= 0 && x0 < 96 && y1 >= 0 && y1 < 96);
    bool vrt = (x1 >= 0 && x1 < 96 && y0 >= 0 && y0 < 96);
    int4 id;
    id.x = vlt ? x0 * 96 + y0 : 0;
    id.y = vrb ? x1 * 96 + y1 : 0;
    id.z = vlb ? x0 * 96 + y1 : 0;
    id.w = vrt ? x1 * 96 + y0 : 0;
    idx4[idx] = id;
    wgt4[idx] = make_float4(vlt ? glt : 0.f, vrb ? grb : 0.f,
                            vlb ? glb : 0.f, vrt ? grt : 0.f);
}

// ---- deformable conv MFMA: cs-outer/kk-inner, XCD-swizzled, tables in LDS ----
// 1D grid 576: xcd = s&7 owns one (b,half) combo; 72 p-tiles per XCD.
__global__ __launch_bounds__(256) void k_dconv(const float* __restrict__ x,
                                               const ushort* __restrict__ wt2h,
                                               const ushort* __restrict__ wt2l,
                                               const int4* __restrict__ idx4,
                                               const float4* __restrict__ wgt4,
                                               float* __restrict__ qpart) {
    int s = blockIdx.x;
    int xcd = s & 7, ib = s >> 3;
    int combo = xcd >> 1;
    int b = combo & 1;
    int half = combo >> 1;
    int p0 = ((xcd & 1) * 72 + ib) * 64;
    int t = threadIdx.x;
    int l = t & 63, w = t >> 6;
    int lrow = l & 15, lhi = l >> 4;
    int obase = w * 64;
    int p = t & 63, cg = t >> 6;

    __shared__ __align__(16) ushort Sh[64 * 40];
    __shared__ __align__(16) ushort Sl[64 * 40];
    __shared__ int4 Tid[9][64];
    __shared__ float4 Twg[9][64];

    // load bilinear tables once per block
    for (int e = t; e < 9 * 64; e += 256) {
        int kk = e >> 6, pl = e & 63;
        size_t tb = ((size_t)b * 9 + kk) * PP + p0 + pl;
        Tid[kk][pl] = idx4[tb];
        Twg[kk][pl] = wgt4[tb];
    }

    f32x4 acc[4][4];
#pragma unroll
    for (int mf = 0; mf < 4; ++mf)
#pragma unroll
        for (int nf = 0; nf < 4; ++nf) acc[mf][nf] = (f32x4)0.f;

    const float* xb = x + (size_t)b * CC * PP;

#pragma unroll 1
    for (int cs = 0; cs < 4; ++cs) {
        int csg = half * 4 + cs;
        const float* xp0 = xb + (size_t)(csg * 32 + cg * 8) * PP;
#pragma unroll 1
        for (int kk = 0; kk < 9; ++kk) {
            __syncthreads();   // prior S reads done (also covers table init)
            bf16x8 ah[4], al[4];
#pragma unroll
            for (int mf = 0; mf < 4; ++mf) {
                size_t gi = (((size_t)(kk * 8 + csg)) * 1024 + (lrow * 4 + lhi + (w * 4 + mf) * 64)) * 8;
                ah[mf] = *(const bf16x8*)&wt2h[gi];
                al[mf] = *(const bf16x8*)&wt2l[gi];
            }
            int4 id = Tid[kk][p];
            float4 g4 = Twg[kk][p];
            bf16x8 vh, vl;
#pragma unroll
            for (int i = 0; i < 8; ++i) {
                const float* xc = xp0 + (size_t)i * PP;
                float v = g4.x * xc[id.x];
                v = fmaf(g4.y, xc[id.y], v);
                v = fmaf(g4.z, xc[id.z], v);
                v = fmaf(g4.w, xc[id.w], v);
                ushort hh = f2bf_rne(v);
                vh[i] = (short)hh;
                vl[i] = (short)f2bf_rne(v - bf2f(hh));
            }
            *(bf16x8*)&Sh[p * 40 + cg * 8] = vh;
            *(bf16x8*)&Sl[p * 40 + cg * 8] = vl;
            __syncthreads();
            bf16x8 Bh4[4], Bl4[4];
#pragma unroll
            for (int nf = 0; nf < 4; ++nf) {
                Bh4[nf] = *(const bf16x8*)&Sh[(nf * 16 + lrow) * 40 + lhi * 8];
                Bl4[nf] = *(const bf16x8*)&Sl[(nf * 16 + lrow) * 40 + lhi * 8];
            }
#pragma unroll
            for (int mf = 0; mf < 4; ++mf) {
#pragma unroll
                for (int nf = 0; nf < 4; ++nf) {
                    acc[mf][nf] = __builtin_amdgcn_mfma_f32_16x16x32_bf16(ah[mf], Bh4[nf], acc[mf][nf], 0, 0, 0);
                    acc[mf][nf] = __builtin_amdgcn_mfma_f32_16x16x32_bf16(ah[mf], Bl4[nf], acc[mf][nf], 0, 0, 0);
                    acc[mf][nf] = __builtin_amdgcn_mfma_f32_16x16x32_bf16(al[mf], Bh4[nf], acc[mf][nf], 0, 0, 0);
                }
            }
        }
    }
    float* qh = qpart + (size_t)half * BB * CC * PP + (size_t)b * CC * PP;
#pragma unroll
    for (int mf = 0; mf < 4; ++mf)
#pragma unroll
        for (int nf = 0; nf < 4; ++nf)
#pragma unroll
            for (int j = 0; j < 4; ++j)
                qh[(size_t)(obase + mf * 16 + lhi * 4 + j) * PP + p0 + nf * 16 + lrow] =
                    acc[mf][nf][j];
}

// ---- generic MFMA GEMM: C[b][mt*256+o][p] = sum_c W[o][c]*B[b][c][p], split bf16 ----
// mtiles==2: 576 blocks, xcd owns (b,mt); mtiles==1: 288 blocks, xcd pair owns b.
__global__ __launch_bounds__(256) void k_gemm_bf(const float* __restrict__ Bsrc,
                                                 const ushort* __restrict__ A2h,
                                                 const ushort* __restrict__ A2l,
                                                 float* __restrict__ C,
                                                 int mtiles) {
    int s = blockIdx.x;
    int xcd = s & 7, ib = s >> 3;
    int b, mt, ptile;
    if (mtiles == 2) {
        int combo = xcd >> 1;
        b = combo & 1; mt = combo >> 1;
        ptile = (xcd & 1) * 72 + ib;
    } else {
        b = xcd >> 2; mt = 0;
        ptile = (xcd & 3) * 36 + ib;
    }
    int p0 = ptile * 64;
    int t = threadIdx.x;
    int l = t & 63, w = t >> 6;
    int lrow = l & 15, lhi = l >> 4;
    int obase = w * 64;
    int p = t & 63, cg = t >> 6;
    __shared__ __align__(16) ushort Sh[64 * 40];
    __shared__ __align__(16) ushort Sl[64 * 40];
    f32x4 acc[4][4];
#pragma unroll
    for (int mf = 0; mf < 4; ++mf)
#pragma unroll
        for (int nf = 0; nf < 4; ++nf) acc[mf][nf] = (f32x4)0.f;
    const float* Bb = Bsrc + (size_t)b * 256 * PP;
#pragma unroll 1
    for (int csg = 0; csg < 8; ++csg) {
        __syncthreads();
        bf16x8 ah[4], al[4];
#pragma unroll
        for (int mf = 0; mf < 4; ++mf) {
            size_t gi = (((size_t)(mt * 8 + csg)) * 1024 + (lrow * 4 + lhi + (w * 4 + mf) * 64)) * 8;
            ah[mf] = *(const bf16x8*)&A2h[gi];
            al[mf] = *(const bf16x8*)&A2l[gi];
        }
        const float* xr = Bb + (size_t)(csg * 32 + cg * 8) * PP + p0 + p;
        bf16x8 vh, vl;
#pragma unroll
        for (int i = 0; i < 8; ++i) {
            float v = xr[(size_t)i * PP];
            ushort hh = f2bf_rne(v);
            vh[i] = (short)hh;
            vl[i] = (short)f2bf_rne(v - bf2f(hh));
        }
        *(bf16x8*)&Sh[p * 40 + cg * 8] = vh;
        *(bf16x8*)&Sl[p * 40 + cg * 8] = vl;
        __syncthreads();
        bf16x8 Bh4[4], Bl4[4];
#pragma unroll
        for (int nf = 0; nf < 4; ++nf) {
            Bh4[nf] = *(const bf16x8*)&Sh[(nf * 16 + lrow) * 40 + lhi * 8];
            Bl4[nf] = *(const bf16x8*)&Sl[(nf * 16 + lrow) * 40 + lhi * 8];
        }
#pragma unroll
        for (int mf = 0; mf < 4; ++mf) {
#pragma unroll
            for (int nf = 0; nf < 4; ++nf) {
                acc[mf][nf] = __builtin_amdgcn_mfma_f32_16x16x32_bf16(ah[mf], Bh4[nf], acc[mf][nf], 0, 0, 0);
                acc[mf][nf] = __builtin_amdgcn_mfma_f32_16x16x32_bf16(ah[mf], Bl4[nf], acc[mf][nf], 0, 0, 0);
                acc[mf][nf] = __builtin_amdgcn_mfma_f32_16x16x32_bf16(al[mf], Bh4[nf], acc[mf][nf], 0, 0, 0);
            }
        }
    }
    float* Cb = C + (size_t)b * (mtiles * 256) * PP;
#pragma unroll
    for (int mf = 0; mf < 4; ++mf)
#pragma unroll
        for (int nf = 0; nf < 4; ++nf)
#pragma unroll
            for (int j = 0; j < 4; ++j)
                Cb[(size_t)(mt * 256 + obase + mf * 16 + lhi * 4 + j) * PP + p0 + nf * 16 + lrow] =
                    acc[mf][nf][j];
}

// ---- row norms of k,v -> 1/max(||row||, 1e-12) ----
__global__ __launch_bounds__(256) void k_norms(const float* __restrict__ kv,
                                               float* __restrict__ invn) {
    int b = blockIdx.y, r = blockIdx.x;
    const float* row = kv + ((size_t)b * 512 + r) * PP;
    int t = threadIdx.x;
    float s = 0.f;
    for (int p = t * 4; p < PP; p += 1024) {
        float4 v = *(const float4*)&row[p];
        s += v.x * v.x + v.y * v.y + v.z * v.z + v.w * v.w;
    }
#pragma unroll
    for (int o = 32; o > 0; o >>= 1) s += __shfl_down(s, o, 64);
    __shared__ float wsum[4];
    if ((t & 63) == 0) wsum[t >> 6] = s;
    __syncthreads();
    if (t == 0) {
        float tot = wsum[0] + wsum[1] + wsum[2] + wsum[3];
        invn[b * 512 + r] = 1.f / fmaxf(sqrtf(tot), 1e-12f);
    }
}

// ---- attention score partials: q . k over 256-p chunks ----
__global__ __launch_bounds__(256) void k_attn_part(const float* __restrict__ qp,
                                                   const float* __restrict__ kv,
                                                   float* __restrict__ apart) {
    int ch = blockIdx.x, h = blockIdx.y, b = blockIdx.z;
    int t = threadIdx.x;
    int d = t & 31, cg = t >> 5;
    __shared__ float qs[32][37], ks[32][37];
    float acc[4] = {0.f, 0.f, 0.f, 0.f};
    const float* q0 = qp + ((size_t)b * CC + h * 32) * PP;
    const float* q1 = q0 + (size_t)BB * CC * PP;
    const float* kb = kv + ((size_t)b * 512 + h * 32) * PP;
    int r = t >> 3, cq = (t & 7) * 4;
    for (int po = ch * 256; po < ch * 256 + 256; po += 32) {
        float4 va = *(const float4*)&q0[(size_t)r * PP + po + cq];
        float4 vb = *(const float4*)&q1[(size_t)r * PP + po + cq];
        qs[r][cq + 0] = va.x + vb.x; qs[r][cq + 1] = va.y + vb.y;
        qs[r][cq + 2] = va.z + vb.z; qs[r][cq + 3] = va.w + vb.w;
        float4 vk = *(const float4*)&kb[(size_t)r * PP + po + cq];
        ks[r][cq + 0] = vk.x; ks[r][cq + 1] = vk.y;
        ks[r][cq + 2] = vk.z; ks[r][cq + 3] = vk.w;
        __syncthreads();
#pragma unroll
        for (int pq = 0; pq < 32; ++pq) {
            float kvv = ks[d][pq];
#pragma unroll
            for (int i = 0; i < 4; ++i)
                acc[i] = fmaf(qs[cg * 4 + i][pq], kvv, acc[i]);
        }
        __syncthreads();
    }
    float* ap = apart + (((size_t)(b * 8 + h) * NCH + ch) << 10);
#pragma unroll
    for (int i = 0; i < 4; ++i) ap[(cg * 4 + i) * 32 + d] = acc[i];
}

// ---- reduce partials, temp*invnk scale, softmax, *invnv ----
__global__ __launch_bounds__(256) void k_attn_fin(const float* __restrict__ apart,
                                                  const float* __restrict__ invn,
                                                  const float* __restrict__ temp,
                                                  float* __restrict__ attns) {
    int h = blockIdx.x, b = blockIdx.y;
    int t = threadIdx.x;
    __shared__ float A[32][33];
    const float* ap = apart + ((size_t)(b * 8 + h) * NCH << 10);
    float th = temp[h];
    for (int e = t; e < 1024; e += 256) {
        float s = 0.f;
        for (int chn = 0; chn < NCH; ++chn) s += ap[chn * 1024 + e];
        int c = e >> 5, d = e & 31;
        A[c][d] = s * th * invn[b * 512 + h * 32 + d];
    }
    __syncthreads();
    if (t < 32) {
        int c = t;
        float m = -INFINITY;
#pragma unroll
        for (int d = 0; d < 32; ++d) m = fmaxf(m, A[c][d]);
        float sum = 0.f;
#pragma unroll
        for (int d = 0; d < 32; ++d) sum += expf(A[c][d] - m);
        float inv = 1.f / sum;
        float* at = attns + ((size_t)(b * 8 + h) << 10) + c * 32;
#pragma unroll
        for (int d = 0; d < 32; ++d)
            at[d] = expf(A[c][d] - m) * inv * invn[b * 512 + 256 + h * 32 + d];
    }
}

// ---- mid = attnS @ v (per head, K=32) ----
__global__ __launch_bounds__(256) void k_outmid(const float* __restrict__ attns,
                                                const float* __restrict__ kv,
                                                float* __restrict__ mid) {
    int pt = blockIdx.x, h = blockIdx.y, b = blockIdx.z;
    int p0 = pt * 128;
    int t = threadIdx.x;
    int tp = t & 31, tc = t >> 5;
    __shared__ float vs[32][132];
    __shared__ float as[32][33];
    for (int e = t; e < 1024; e += 256)
        as[e >> 5][e & 31] = attns[((size_t)(b * 8 + h) << 10) + e];
    {
        int r = t & 31;
        int c0 = (t >> 5) * 16;
        const float* vrow = kv + ((size_t)b * 512 + 256 + h * 32 + r) * PP + p0;
#pragma unroll
        for (int kq = 0; kq < 4; ++kq)
            *(float4*)&vs[r][c0 + kq * 4] = *(const float4*)&vrow[c0 + kq * 4];
    }
    __syncthreads();
    float acc[4][4];
#pragma unroll
    for (int i = 0; i < 4; ++i)
#pragma unroll
        for (int j = 0; j < 4; ++j) acc[i][j] = 0.f;
#pragma unroll
    for (int d = 0; d < 32; ++d) {
        float4 bv = *(const float4*)&vs[d][tp * 4];
#pragma unroll
        for (int i = 0; i < 4; ++i) {
            float a = as[tc * 4 + i][d];
            acc[i][0] = fmaf(a, bv.x, acc[i][0]);
            acc[i][1] = fmaf(a, bv.y, acc[i][1]);
            acc[i][2] = fmaf(a, bv.z, acc[i][2]);
            acc[i][3] = fmaf(a, bv.w, acc[i][3]);
        }
    }
#pragma unroll
    for (int i = 0; i < 4; ++i) {
        float* mrow = mid + ((size_t)b * CC + h * 32 + tc * 4 + i) * PP + p0 + tp * 4;
        *(float4*)mrow = make_float4(acc[i][0], acc[i][1], acc[i][2], acc[i][3]);
    }
}

extern "C" void kernel_launch(void* const* d_in, const int* in_sizes, int n_in,
                              void* d_out, int out_size, void* d_ws, size_t ws_size,
                              hipStream_t stream) {
    const float* x     = (const float*)d_in[0];
    const float* wp    = (const float*)d_in[1];
    const float* bp    = (const float*)d_in[2];
    const float* wd    = (const float*)d_in[3];
    const float* wqkv  = (const float*)d_in[4];
    const float* temp  = (const float*)d_in[5];
    const float* wproj = (const float*)d_in[6];
    float* out = (float*)d_out;
    float* ws  = (float*)d_ws;

    float* off    = ws + OFF_O;
    int4*  idx4   = (int4*)(ws + IDX_O);
    float4* wgt4  = (float4*)(ws + WGT_O);
    ushort* wt2h  = (ushort*)(ws + WT2_O);
    ushort* wt2l  = wt2h + 9 * 8 * 1024 * 8;
    ushort* wp2h  = (ushort*)(ws + WP2_O);
    ushort* wp2l  = wp2h + 9 * 8 * 128 * 8;
    ushort* wq2h  = (ushort*)(ws + WQ2_O);
    ushort* wq2l  = wq2h + 2 * 8 * 1024 * 8;
    ushort* wpr2h = (ushort*)(ws + WPR2_O);
    ushort* wpr2l = wpr2h + 8 * 1024 * 8;
    float* qpart  = ws + QP_O;   // aliases ppart and mid (sequential lifetimes)
    float* ppart  = ws + QP_O;
    float* mid    = ws + QP_O;
    float* kv     = ws + KV_O;
    float* invn   = ws + INV_O;
    float* apart  = ws + AP_O;
    float* attns  = ws + AT_O;

    k_prep_wt<<<2304, 256, 0, stream>>>(wd, wt2h, wt2l);
    k_prep_wp<<<288, 256, 0, stream>>>(wp, wp2h, wp2l);
    k_prep_w<<<512, 256, 0, stream>>>(wqkv + 256 * 256, wq2h, wq2l, 2 * 65536);
    k_prep_w<<<256, 256, 0, stream>>>(wproj, wpr2h, wpr2l, 65536);
    k_pconv<<<1152, 256, 0, stream>>>(x, wp2h, wp2l, ppart);
    k_pred<<<(BB * KO * PP + 255) / 256, 256, 0, stream>>>(ppart, bp, off);
    k_bilin<<<(BB * 9 * PP + 255) / 256, 256, 0, stream>>>(off, idx4, wgt4);
    k_dconv<<<576, 256, 0, stream>>>(x, wt2h, wt2l, idx4, wgt4, qpart);
    k_gemm_bf<<<576, 256, 0, stream>>>(x, wq2h, wq2l, kv, 2);
    k_norms<<<dim3(512, BB), 256, 0, stream>>>(kv, invn);
    k_attn_part<<<dim3(NCH, HEADS, BB), 256, 0, stream>>>(qpart, kv, apart);
    k_attn_fin<<<dim3(HEADS, BB), 256, 0, stream>>>(apart, invn, temp, attns);
    k_outmid<<<dim3(72, HEADS, BB), 256, 0, stream>>>(attns, kv, mid);
    k_gemm_bf<<<288, 256, 0, stream>>>(mid, wpr2h, wpr2l, out, 1);
}